// Round 7
// baseline (557.876 us; speedup 1.0000x reference)
//
#include <hip/hip_runtime.h>
#include <math.h>

#define NBATCH 4096
#define NH2 21
#define NK 77
#define NC 35
#define NIJ 441
#define Y_SIZE 33957
#define M_SIZE 5929
#define VOLOFF Y_SIZE          // vol[n] at out[VOLOFF + n] (temp, inside M region)
#define VSUM (Y_SIZE + 4096)   // volsum at out[VSUM] (temp, inside M region)
#define NPAIR 231              // upper-triangular (i<=j) pairs of 21
#define BLK 512                // contract block threads (8 waves)
#define NPB 8                  // n per contract block
#define GRID_B (NBATCH / NPB)  // 512 blocks
#define EIGT 640               // fused eig block: 10 waves (bisect phase)

// workspace layout (d_ws): NSLOT partial-S slots
#define NSLOT 16
#define SLOT_STRIDE 17792      // NPAIR*NK=17787 padded
#define WS2OFF (NSLOT * SLOT_STRIDE)   // 284672 floats; ws total ~1.14 MB

#define SZ_OMEGA  (NBATCH * NH2 * NH2)   // 1,806,336
#define SZ_PHI    (NBATCH * NK * NC)     // 11,038,720
#define SZ_METRIC (NBATCH * 7 * 7)       // 200,704

// ---------------- compile-time wedge structure constants ----------------
// C[a,b,c] nonzero iff pair_a, pair_b, triple_c partition {0..6}; value = perm
// sign. Exactly 6 (a,b) terms per c. MUST be a constexpr LOCAL in each kernel
// (round-3 finding). C[a,b,c]=C[b,a,c] => S symmetric in (i,j): only i<=j pairs.
// R5: never cap VGPRs below live set (spill -> 5x).
// R12: shfl == ds_bpermute ~120-150cy LDS hop; DPP adds ~5cy.
// R13: single-WAVE tridiag (A in VGPRs, zero barriers) = 138us.
// R14: literal row select + v_pk_fma + gram 77-block: 114us.
// R15 FAILED (+7us): volatile pk_fma pins order; scheduler can't interleave.
// R16: non-volatile asm + oct-sigma + readlane-x1 + sqrt/rcp builtins: 107.6.
//   VALUBusy*t unchanged vs R14 => issue count stable; win was chain length.
//   Wave runs ~48% VALU duty: half issue, half dependency stall.
// R17: (a) precompute next-iter scalars (sigma2/x1/alpha/beta/xha) at the END
//   of iteration k, overlapped with the 9-row update (bit-identical values —
//   same rc, same formulas, just moved); head becomes vc->matvec directly.
//   (b) fuse bisect into the tridiag kernel (wave 0 tridiag -> LDS d/e ->
//   barrier -> 640-thread 9-section bisect): one less dispatch, no global
//   d/e roundtrip. 148 VGPR < 170 cap at 10 waves/CU (3/SIMD).
// R7: LDS strides sharing a factor with the bank-group period -> conflicts.
// R8: 2-barrier staged VALU loop plateaus ~27% VALUBusy -> moved to MFMA (R9).
struct WTab {
  int a[NC][6];
  int b[NC][6];
  int sg[NC][6];
};

constexpr WTab make_wtab() {
  WTab W{};
  int p0[21] = {}, p1[21] = {};
  int idx = 0;
  for (int x = 0; x < 7; ++x)
    for (int y = x + 1; y < 7; ++y) { p0[idx] = x; p1[idx] = y; ++idx; }
  int t0[35] = {}, t1[35] = {}, t2[35] = {};
  idx = 0;
  for (int x = 0; x < 7; ++x)
    for (int y = x + 1; y < 7; ++y)
      for (int z = y + 1; z < 7; ++z) { t0[idx] = x; t1[idx] = y; t2[idx] = z; ++idx; }
  int cnt[35] = {};
  for (int a = 0; a < 21; ++a)
    for (int b = 0; b < 21; ++b) {
      int pa0 = p0[a], pa1 = p1[a], pb0 = p0[b], pb1 = p1[b];
      if (pa0 == pb0 || pa0 == pb1 || pa1 == pb0 || pa1 == pb1) continue;
      bool used[7] = {};
      used[pa0] = true; used[pa1] = true; used[pb0] = true; used[pb1] = true;
      int tr[3] = {}; int k = 0;
      for (int x = 0; x < 7; ++x) if (!used[x]) tr[k++] = x;
      int c = -1;
      for (int cc = 0; cc < 35; ++cc)
        if (t0[cc] == tr[0] && t1[cc] == tr[1] && t2[cc] == tr[2]) { c = cc; break; }
      int perm[7] = {pa0, pa1, pb0, pb1, tr[0], tr[1], tr[2]};
      int inv = 0;
      for (int i = 0; i < 7; ++i)
        for (int j = i + 1; j < 7; ++j)
          if (perm[i] > perm[j]) ++inv;
      W.a[c][cnt[c]] = a; W.b[c][cnt[c]] = b; W.sg[c][cnt[c]] = (inv & 1) ? -1 : 1;
      ++cnt[c];
    }
  return W;
}

__device__ __forceinline__ int trioff(int i) { return 21 * i - (i * (i - 1)) / 2; }

// fp32 -> bf16 (RNE), returns low 16 bits
__device__ __forceinline__ unsigned f2bf(float x) {
  union { float f; unsigned u; } v; v.f = x;
  return ((v.u + 0x7FFFu + ((v.u >> 16) & 1u)) >> 16) & 0xFFFFu;
}

typedef float f32x4 __attribute__((ext_vector_type(4)));
typedef float f32x2 __attribute__((ext_vector_type(2)));
typedef short s16x8 __attribute__((ext_vector_type(8)));

// packed fp32 FMA (VOP3P, gfx90a+): d = a*b + c per 32-bit half. NOT volatile.
__device__ __forceinline__ f32x2 pk_fma(f32x2 a, f32x2 b, f32x2 c) {
  f32x2 d;
  asm("v_pk_fma_f32 %0, %1, %2, %3" : "=v"(d) : "v"(a), "v"(b), "v"(c));
  return d;
}

// ---------------- DPP wave reductions (R12): VALU-latency, no LDS pipe -------
template <int CTRL>
__device__ __forceinline__ float dppadd(float x) {
  union { float f; int i; } u, r;
  u.f = x;
  r.i = __builtin_amdgcn_update_dpp(0, u.i, CTRL, 0xF, 0xF, true);
  return x + r.f;
}
// sum over each aligned group of 8 lanes; result in ALL 8 lanes of the group
__device__ __forceinline__ float oct_sum(float x) {
  x = dppadd<0xB1>(x);    // quad_perm(1,0,3,2)  : + xor1
  x = dppadd<0x4E>(x);    // quad_perm(2,3,0,1)  : + xor2
  x = dppadd<0x141>(x);   // row_half_mirror     : + other quad of 8
  return x;
}
// sum over all 64 lanes; result valid in lane 63
__device__ __forceinline__ float wave_sum(float x) {
  x = dppadd<0xB1>(x);
  x = dppadd<0x4E>(x);
  x = dppadd<0x141>(x);
  x = dppadd<0x140>(x);   // row_mirror
  x = dppadd<0x142>(x);   // row_bcast15
  x = dppadd<0x143>(x);   // row_bcast31
  return x;
}
__device__ __forceinline__ float readlane63(float x) {
  union { float f; int i; } u; u.f = x;
  union { int i; float f; } r;
  r.i = __builtin_amdgcn_readlane(u.i, 63);
  return r.f;
}
__device__ __forceinline__ float readlane0(float x) {
  union { float f; int i; } u; u.f = x;
  union { int i; float f; } r;
  r.i = __builtin_amdgcn_readfirstlane(u.i);
  return r.f;
}
__device__ __forceinline__ float readlaneN(float x, int lane) {
  union { float f; int i; } u; u.f = x;
  union { int i; float f; } r;
  r.i = __builtin_amdgcn_readlane(u.i, lane);
  return r.f;
}

// ---------------- kernel A: vol[n] = sqrt(|det(metric_n)|), + sum ----------------
__global__ __launch_bounds__(256) void vol_kernel(const float* __restrict__ metric,
                                                  float* __restrict__ out) {
  const int n = blockIdx.x * 256 + threadIdx.x;
  double a[7][7];
#pragma unroll
  for (int r = 0; r < 7; ++r)
#pragma unroll
    for (int c = 0; c < 7; ++c) a[r][c] = (double)metric[n * 49 + r * 7 + c];

  double det = 1.0;
#pragma unroll
  for (int k = 0; k < 7; ++k) {
#pragma unroll
    for (int r = k + 1; r < 7; ++r) {
      bool sw = fabs(a[r][k]) > fabs(a[k][k]);
#pragma unroll
      for (int c = k; c < 7; ++c) {
        double u = a[k][c], v = a[r][c];
        a[k][c] = sw ? v : u;
        a[r][c] = sw ? u : v;
      }
    }
    det *= a[k][k];
    double inv = (a[k][k] != 0.0) ? 1.0 / a[k][k] : 0.0;
#pragma unroll
    for (int r = k + 1; r < 7; ++r) {
      double f = a[r][k] * inv;
#pragma unroll
      for (int c = k + 1; c < 7; ++c) a[r][c] -= f * a[k][c];
    }
  }
  float vol = (float)sqrt(fabs(det));
  out[VOLOFF + n] = vol;

  float s = vol;
#pragma unroll
  for (int off = 32; off > 0; off >>= 1) s += __shfl_down(s, off, 64);
  __shared__ float partial[4];
  const int lane = threadIdx.x & 63, wv = threadIdx.x >> 6;
  if (lane == 0) partial[wv] = s;
  __syncthreads();
  if (threadIdx.x == 0)
    atomicAdd(out + VSUM, partial[0] + partial[1] + partial[2] + partial[3]);
}

// ---------------- kernel B: MFMA contract (R13: slot-partial output) ----------
__global__ __launch_bounds__(BLK) void contract_kernel(const float* __restrict__ omega,
                                                       const float* __restrict__ Phi,
                                                       const float* __restrict__ out,
                                                       float* __restrict__ wsS) {
  constexpr WTab W = make_wtab();
  __shared__ __align__(16) short ldsD[256 * 80];  // D rows, stride 80 bf16
  __shared__ __align__(16) short ldsP[80 * 80];   // PW^T rows [q][k], stride 80
  __shared__ __align__(16) float ldsO[NH2 * 28];  // omega rows, stride 28 fp32

  const int t = threadIdx.x;
  const int lane = t & 63;
  const int wv = t >> 6;
  const int quad = lane >> 4;
  const int col = lane & 15;
  const int n0 = blockIdx.x * NPB;

  for (int f = t; f < 256 * 40; f += BLK) ((int*)ldsD)[f] = 0;
  for (int f = t; f < 80 * 40; f += BLK) ((int*)ldsP)[f] = 0;

  const bool roleA = (t < NPAIR);
  const bool roleB = (t >= 256) && (t < 256 + NPAIR);
  int pi = 0, pj = 0;
  {
    const int p = roleA ? t : (roleB ? (t - 256) : 0);
    int i = 0;
    while (i < 20 && trioff(i + 1) <= p) ++i;
    pi = i;
    pj = p - trioff(i) + i;
  }

  float rA = 0.0f, rB[6], rvn;
  {
    const float* om = omega + n0 * 441;
    const float* ph = Phi + n0 * 2695;
    if (t < 441) rA = om[t];
#pragma unroll
    for (int j = 0; j < 6; ++j) {
      const int e = t + j * BLK;
      rB[j] = (e < 2695) ? ph[e] : 0.0f;
    }
    rvn = out[VOLOFF + n0];
  }

  f32x4 acc[2][5];
#pragma unroll
  for (int mi = 0; mi < 2; ++mi)
#pragma unroll
    for (int nt = 0; nt < 5; ++nt) acc[mi][nt] = (f32x4){0.f, 0.f, 0.f, 0.f};

  for (int it = 0; it < NPB; ++it) {
    __syncthreads();

    if (t < 441) ldsO[(t / 21) * 28 + (t % 21)] = rA;
    {
      const float vn = rvn;
#pragma unroll
      for (int j = 0; j < 6; ++j) {
        const int e = t + j * BLK;
        if (e < 2695) {
          const int q = e / 35, c = e % 35;
          ldsP[q * 80 + c] = (short)f2bf(vn * rB[j]);
        }
      }
    }
    __syncthreads();

    if (it + 1 < NPB) {
      const int n1 = n0 + it + 1;
      const float* om2 = omega + n1 * 441;
      const float* ph2 = Phi + n1 * 2695;
      if (t < 441) rA = om2[t];
#pragma unroll
      for (int j = 0; j < 6; ++j) {
        const int e = t + j * BLK;
        if (e < 2695) rB[j] = ph2[e];
      }
      rvn = out[VOLOFF + n1];
    }

    if (roleA || roleB) {
      float wi[21], wj[21];
      const float* oi = ldsO + pi * 28;
      const float* oj = ldsO + pj * 28;
#pragma unroll
      for (int a = 0; a < 20; a += 4) {
        float4 v = *(const float4*)(oi + a);
        wi[a] = v.x; wi[a + 1] = v.y; wi[a + 2] = v.z; wi[a + 3] = v.w;
        float4 u = *(const float4*)(oj + a);
        wj[a] = u.x; wj[a + 1] = u.y; wj[a + 2] = u.z; wj[a + 3] = u.w;
      }
      wi[20] = oi[20]; wj[20] = oj[20];

      if (roleA) {
        float d[18];
#pragma unroll
        for (int c = 0; c < 18; ++c) {
          float dd = 0.0f;
#pragma unroll
          for (int u = 0; u < 6; ++u)
            dd = fmaf((W.sg[c][u] > 0) ? wi[W.a[c][u]] : -wi[W.a[c][u]], wj[W.b[c][u]], dd);
          d[c] = dd;
        }
        int* Drow = (int*)ldsD + t * 40;
#pragma unroll
        for (int k2 = 0; k2 < 9; ++k2)
          Drow[k2] = (int)(f2bf(d[2 * k2]) | (f2bf(d[2 * k2 + 1]) << 16));
      } else {
        float d[17];
#pragma unroll
        for (int c = 18; c < 35; ++c) {
          float dd = 0.0f;
#pragma unroll
          for (int u = 0; u < 6; ++u)
            dd = fmaf((W.sg[c][u] > 0) ? wi[W.a[c][u]] : -wi[W.a[c][u]], wj[W.b[c][u]], dd);
          d[c - 18] = dd;
        }
        int* Drow = (int*)ldsD + (t - 256) * 40;
#pragma unroll
        for (int k2 = 0; k2 < 8; ++k2)
          Drow[9 + k2] = (int)(f2bf(d[2 * k2]) | (f2bf(d[2 * k2 + 1]) << 16));
        Drow[17] = (int)f2bf(d[16]);
      }
    }
    __syncthreads();

#pragma unroll
    for (int s = 0; s < 2; ++s) {
      const int kof = s * 32 + quad * 8;
      s16x8 a0 = *(const s16x8*)(ldsD + ((wv * 2 + 0) * 16 + col) * 80 + kof);
      s16x8 a1 = *(const s16x8*)(ldsD + ((wv * 2 + 1) * 16 + col) * 80 + kof);
      s16x8 b[5];
#pragma unroll
      for (int nt = 0; nt < 5; ++nt)
        b[nt] = *(const s16x8*)(ldsP + (nt * 16 + col) * 80 + kof);
#pragma unroll
      for (int nt = 0; nt < 5; ++nt) {
        acc[0][nt] = __builtin_amdgcn_mfma_f32_16x16x32_bf16(a0, b[nt], acc[0][nt], 0, 0, 0);
        acc[1][nt] = __builtin_amdgcn_mfma_f32_16x16x32_bf16(a1, b[nt], acc[1][nt], 0, 0, 0);
      }
    }
  }

  // R13: scatter into one of NSLOT partial copies (contention /32)
  float* slot = wsS + (size_t)(blockIdx.x & (NSLOT - 1)) * SLOT_STRIDE;
#pragma unroll
  for (int mi = 0; mi < 2; ++mi) {
    const int mt = wv * 2 + mi;
#pragma unroll
    for (int r = 0; r < 4; ++r) {
      const int m = mt * 16 + quad * 4 + r;
      if (m < NPAIR) {
#pragma unroll
        for (int nt = 0; nt < 5; ++nt) {
          const int q = nt * 16 + col;
          if (q < 77) atomicAdd(&slot[m * NK + q], acc[mi][nt][r]);
        }
      }
    }
  }
}

// ---------------- kernel C1: finalize Y from slot partials ----------------
__global__ __launch_bounds__(256) void finalize_y(const float* __restrict__ wsS,
                                                  float* __restrict__ out) {
  const int e = blockIdx.x * 256 + threadIdx.x;
  if (e >= NPAIR * NK) return;
  const int p = e / NK, k = e % NK;
  int i = 0;
  while (i < 20 && trioff(i + 1) <= p) ++i;
  const int j = p - trioff(i) + i;
  float v = 0.0f;
#pragma unroll
  for (int s = 0; s < NSLOT; ++s) v += wsS[(size_t)s * SLOT_STRIDE + p * NK + k];
  v *= 1.0f / out[VSUM];
  out[(i * 21 + j) * NK + k] = v;
  if (j != i) out[(j * 21 + i) * NK + k] = -v;
}

// ---------------- kernel C2: M[k,l] = sum_ij Y_ij,k Y_ij,l (R14) ----------------
__global__ __launch_bounds__(EIGT) void gram_kernel(const float* __restrict__ Y,
                                                    float* __restrict__ Mout) {
  const int k = blockIdx.x;
  const int t = threadIdx.x;
  const int l = t >> 3, s = t & 7;
  float acc = 0.0f;
  if (l < NK) {
    for (int ij = s; ij < NIJ; ij += 8)
      acc = fmaf(Y[ij * NK + k], Y[ij * NK + l], acc);
  }
  acc = oct_sum(acc);
  if (s == 0 && l < NK) Mout[k * NK + l] = acc;
}

// next-iteration scalar precompute (R17): uses the freshly-broadcast rc (row
// KN), indices O2/B2 literal/semi-literal so rc[O2] stays a register ref.
#define PRECOMP(KN, O2, B2)                                                   \
  do {                                                                        \
    float pt_ = 0.0f;                                                         \
    if (br == 0) {                                                            \
      _Pragma("unroll") for (int c2_ = 0; c2_ < 5; ++c2_) {                   \
        const int gc0_ = 10 * bc + 2 * c2_;                                   \
        const float x0_ = rc[2 * c2_], xv_ = rc[2 * c2_ + 1];                 \
        pt_ += (gc0_ > (KN)) ? x0_ * x0_ : 0.0f;                              \
        pt_ += (gc0_ + 1 > (KN)) ? xv_ * xv_ : 0.0f;                          \
      }                                                                       \
    }                                                                         \
    pt_ = oct_sum(pt_);                                                       \
    sig2c = readlane0(pt_);                                                   \
    const float x1n_ = readlaneN(rc[(O2)], (B2));                             \
    const float sg_ = __builtin_amdgcn_sqrtf(sig2c);                          \
    alpha_c = (x1n_ >= 0.0f) ? -sg_ : sg_;                                    \
    beta_c = __builtin_amdgcn_rcpf(fmaf(-alpha_c, x1n_, sig2c));              \
    xha_c = x1n_ - alpha_c;                                                   \
  } while (0)

// ---------------- kernel D: fused tridiag (wave 0) + bisect (10 waves) --------
// Wave 0: single-wave Householder, A[80x80] in VGPRs as f32x2 col-pairs; lane
// l=(br<<3)|bc owns rows [10br,+10) x col-pairs [5bc,+5). Zero barriers in the
// k-loop. R17: next-iter scalars precomputed at iteration end (overlap with
// the 9-row update); head starts at vc->matvec. d/e written to LDS.
// Then __syncthreads and the verified 640-thread 9-section Sturm bisection.
__global__ __launch_bounds__(EIGT, 1) void eig_kernel(const float* __restrict__ Min,
                                                      float* __restrict__ eout) {
  __shared__ float dsh[80], esh[80], e2sh[80];
  __shared__ float red[10], red2[10];
  const int t = threadIdx.x;

  if (t < 64) {
    const int l = t;
    const int br = l >> 3, bc = l & 7;
    f32x2 A2[10][5];
#pragma unroll
    for (int r = 0; r < 10; ++r) {
      const int g = 10 * br + r;
#pragma unroll
      for (int c2 = 0; c2 < 5; ++c2) {
        const int gc0 = 10 * bc + 2 * c2;
        A2[r][c2][0] = (g < 77 && gc0 < 77) ? Min[g * 77 + gc0] : 0.0f;
        A2[r][c2][1] = (g < 77 && gc0 + 1 < 77) ? Min[g * 77 + gc0 + 1] : 0.0f;
      }
    }

    // prologue: broadcast row 0 + scalars for k=0
    float rc[10], rr[10];
#pragma unroll
    for (int c2 = 0; c2 < 5; ++c2) {
      rc[2 * c2]     = __shfl(A2[0][c2][0], bc, 64);
      rc[2 * c2 + 1] = __shfl(A2[0][c2][1], bc, 64);
      rr[2 * c2]     = __shfl(A2[0][c2][0], br, 64);
      rr[2 * c2 + 1] = __shfl(A2[0][c2][1], br, 64);
    }
    float sig2c, alpha_c, beta_c, xha_c;
    PRECOMP(0, 1, 0);   // sigma over col>0 of row 0; x1 = A[0][1] (lane 0)

#pragma unroll 1
    for (int kb = 0; kb < 8; ++kb) {
#pragma unroll
      for (int ko = 0; ko < 10; ++ko) {
        if (kb == 7 && ko >= 5) break;         // k stops at 74
        const int k = kb * 10 + ko;
        const int nko = (ko + 1) % 10;         // literal after unroll
        const int nkb = kb + (ko == 9 ? 1 : 0);
        const int nic = nkb * 8 + bc, nir = nkb * 8 + br;
        const int o2 = (ko + 2) % 10;          // col (k+2) local index
        const int b2 = kb + (ko + 2) / 10;     // col (k+2) owner bc

        if (sig2c < 1e-26f) {                  // uniform branch, rare
          if (l == 0) esh[k] = 0.0f;
#pragma unroll
          for (int c2 = 0; c2 < 5; ++c2) {     // row k+1 unchanged; pipeline
            rc[2 * c2]     = __shfl(A2[nko][c2][0], nic, 64);
            rc[2 * c2 + 1] = __shfl(A2[nko][c2][1], nic, 64);
            rr[2 * c2]     = __shfl(A2[nko][c2][0], nir, 64);
            rr[2 * c2 + 1] = __shfl(A2[nko][c2][1], nir, 64);
          }
          PRECOMP(k + 1, o2, b2);
          continue;
        }
        const float beta = beta_c, xha = xha_c;
        if (l == 0) esh[k] = alpha_c;

        // v over own cols (from rc) and own rows (from rr) — both local
        f32x2 vc2[5];
        float vr[10];
#pragma unroll
        for (int c2 = 0; c2 < 5; ++c2) {
          const int gc0 = 10 * bc + 2 * c2;
          vc2[c2][0] = (gc0 > k) ? ((gc0 == k + 1) ? xha : rc[2 * c2]) : 0.0f;
          vc2[c2][1] = (gc0 + 1 > k) ? ((gc0 + 1 == k + 1) ? xha : rc[2 * c2 + 1]) : 0.0f;
          const int gr0 = 10 * br + 2 * c2;
          vr[2 * c2] = (gr0 > k) ? ((gr0 == k + 1) ? xha : rr[2 * c2]) : 0.0f;
          vr[2 * c2 + 1] = (gr0 + 1 > k) ? ((gr0 + 1 == k + 1) ? xha : rr[2 * c2 + 1]) : 0.0f;
        }

        // p = beta * A v (packed fma; rows independent)
        float p[10];
#pragma unroll
        for (int r = 0; r < 10; ++r) {
          f32x2 a = (f32x2){0.f, 0.f};
#pragma unroll
          for (int c2 = 0; c2 < 5; ++c2) a = pk_fma(A2[r][c2], vc2[c2], a);
          p[r] = a[0] + a[1];
        }
#pragma unroll
        for (int r = 0; r < 10; ++r) {
          p[r] = oct_sum(p[r]) * beta;
          p[r] = (10 * br + r > k) ? p[r] : 0.0f;
        }

        // prefetch p-by-columns NOW (hides under the K reduction)
        f32x2 pc2[5];
#pragma unroll
        for (int c2 = 0; c2 < 5; ++c2) {
          pc2[c2][0] = __shfl(p[2 * c2], 9 * bc, 64);
          pc2[c2][1] = __shfl(p[2 * c2 + 1], 9 * bc, 64);
        }

        // K = p . v (rows counted once: bc==0 lanes)
        float kp = 0.0f;
        if (bc == 0) {
#pragma unroll
          for (int r = 0; r < 10; ++r) kp = fmaf(p[r], vr[r], kp);
        }
        kp = wave_sum(kp);
        const float hb = 0.5f * beta * readlane63(kp);

        // w by rows (local); wc by cols LOCAL from prefetched pc
        float w[10];
#pragma unroll
        for (int r = 0; r < 10; ++r) w[r] = fmaf(-hb, vr[r], p[r]);
        const f32x2 mhb = (f32x2){-hb, -hb};
        f32x2 wc2[5];
#pragma unroll
        for (int c2 = 0; c2 < 5; ++c2) wc2[c2] = pk_fma(mhb, vc2[c2], pc2[c2]);

        // rank-2 update: pivot row nko FIRST, issue next broadcast, then rest
        {
          const f32x2 nv = (f32x2){-vr[nko], -vr[nko]};
          const f32x2 nw = (f32x2){-w[nko], -w[nko]};
#pragma unroll
          for (int c2 = 0; c2 < 5; ++c2)
            A2[nko][c2] = pk_fma(nv, wc2[c2], pk_fma(nw, vc2[c2], A2[nko][c2]));
        }
#pragma unroll
        for (int c2 = 0; c2 < 5; ++c2) {
          rc[2 * c2]     = __shfl(A2[nko][c2][0], nic, 64);
          rc[2 * c2 + 1] = __shfl(A2[nko][c2][1], nic, 64);
          rr[2 * c2]     = __shfl(A2[nko][c2][0], nir, 64);
          rr[2 * c2 + 1] = __shfl(A2[nko][c2][1], nir, 64);
        }
#pragma unroll
        for (int r = 0; r < 10; ++r) {
          if (r == nko) continue;
          const f32x2 nv = (f32x2){-vr[r], -vr[r]};
          const f32x2 nw = (f32x2){-w[r], -w[r]};
#pragma unroll
          for (int c2 = 0; c2 < 5; ++c2)
            A2[r][c2] = pk_fma(nv, wc2[c2], pk_fma(nw, vc2[c2], A2[r][c2]));
        }

        // next-iteration scalars, overlapped with the update issue above
        PRECOMP(k + 1, o2, b2);
      }
    }

    // gather tridiagonal into LDS: diag from lanes br==bc, A[76][75] lane 63
    if (br == bc) {
#pragma unroll
      for (int e = 0; e < 10; ++e)
        dsh[10 * br + e] = (e & 1) ? A2[e][e / 2][1] : A2[e][e / 2][0];
    }
    if (l == 63) esh[75] = A2[6][2][1];        // A[76][75]
  }
  __syncthreads();

  // ---------------- bisect phase (verified 9-section, 640 thr) ----------------
  const int lane = t & 63, wv = t >> 6;
  if (t < 76) e2sh[t] = esh[t] * esh[t];

  // Gershgorin bounds (parallel reduce)
  float lo_ = 1e30f, hi_ = -1e30f;
  if (t < 77) {
    const float r = ((t > 0) ? fabsf(esh[t - 1]) : 0.0f) +
                    ((t < 76) ? fabsf(esh[t]) : 0.0f);
    lo_ = dsh[t] - r;
    hi_ = dsh[t] + r;
  }
#pragma unroll
  for (int off = 1; off < 64; off <<= 1) {
    lo_ = fminf(lo_, __shfl_xor(lo_, off, 64));
    hi_ = fmaxf(hi_, __shfl_xor(hi_, off, 64));
  }
  if (lane == 0) { red[wv] = lo_; red2[wv] = hi_; }
  __syncthreads();                          // also fences e2sh/dsh
  lo_ = red[0]; hi_ = red2[0];
#pragma unroll
  for (int u = 1; u < 10; ++u) { lo_ = fminf(lo_, red[u]); hi_ = fmaxf(hi_, red2[u]); }
  const float span = hi_ - lo_;
  const float glo = lo_ - 0.001f * span - 1e-6f;
  const float ghi = hi_ + 0.001f * span + 1e-6f;

  // 9-section search via Sturm count: 8 probe lanes per eigenvalue, 13 rounds
  {
    const int e = t >> 3;        // eigenvalue index 0..79 (77..79 inactive)
    const int s = t & 7;         // probe lane within oct
    const int g = (t & 63) >> 3; // oct group within wave
    float lo = glo, hi = ghi;
    for (int r = 0; r < 13; ++r) {
      const float step = (hi - lo) * (1.0f / 9.0f);
      const float x = fmaf(step, (float)(s + 1), lo);
      float q = dsh[0] - x;
      int cnt = (q < 0.0f);
#pragma unroll 4
      for (int i = 1; i < 77; ++i) {
        q = (fabsf(q) < 1e-30f) ? -1e-30f : q;
        q = dsh[i] - x - e2sh[i - 1] * __builtin_amdgcn_rcpf(q);
        cnt += (q < 0.0f);
      }
      const unsigned long long mask = __ballot(cnt > e);
      const int b = (int)((mask >> (g * 8)) & 0xFFull);
      const int z = b ? __builtin_ctz(b) : 8;   // probes with cnt<=e
      const float nlo = fmaf(step, (float)z, lo);
      hi = (z == 8) ? hi : fmaf(step, (float)(z + 1), lo);
      lo = nlo;
    }
    if (s == 0 && e < 77) eout[76 - e] = 0.5f * (lo + hi);  // descending
  }
}

// ---------------- launch ----------------
extern "C" void kernel_launch(void* const* d_in, const int* in_sizes, int n_in,
                              void* d_out, int out_size, void* d_ws, size_t ws_size,
                              hipStream_t stream) {
  const float* omega  = (const float*)d_in[0];
  const float* Phi    = (const float*)d_in[1];
  const float* metric = (const float*)d_in[2];
  for (int q = 0; q < n_in && q < 3; ++q) {
    if (in_sizes[q] == SZ_OMEGA)       omega  = (const float*)d_in[q];
    else if (in_sizes[q] == SZ_PHI)    Phi    = (const float*)d_in[q];
    else if (in_sizes[q] == SZ_METRIC) metric = (const float*)d_in[q];
  }

  float* out = (float*)d_out;
  float* ws  = (float*)d_ws;   // needs WS2OFF*4 ~ 1.14 MB (slot partials)

  // out[0 .. Y_SIZE)           : finalized Y
  // out[VOLOFF .. VOLOFF+4096) : vol[n] (temp, overwritten by gram's M)
  // out[VSUM]                  : volsum (temp, overwritten by gram's M)
  // ws[0 .. WS2OFF)            : NSLOT partial-S slots
  hipMemsetAsync(d_out, 0, (size_t)out_size * sizeof(float), stream);
  hipMemsetAsync(d_ws, 0, (size_t)WS2OFF * sizeof(float), stream);

  hipLaunchKernelGGL(vol_kernel, dim3(NBATCH / 256), dim3(256), 0, stream, metric, out);
  hipLaunchKernelGGL(contract_kernel, dim3(GRID_B), dim3(BLK), 0, stream,
                     omega, Phi, out, ws);
  hipLaunchKernelGGL(finalize_y, dim3((NPAIR * NK + 255) / 256), dim3(256), 0, stream,
                     ws, out);
  hipLaunchKernelGGL(gram_kernel, dim3(NK), dim3(EIGT), 0, stream,
                     out, out + Y_SIZE);
  hipLaunchKernelGGL(eig_kernel, dim3(1), dim3(EIGT), 0, stream,
                     out + Y_SIZE, out + Y_SIZE + M_SIZE);
}

// Round 8
// 348.468 us; speedup vs baseline: 1.6009x; 1.6009x over previous
//
#include <hip/hip_runtime.h>
#include <math.h>

#define NBATCH 4096
#define NH2 21
#define NK 77
#define NC 35
#define NIJ 441
#define Y_SIZE 33957
#define M_SIZE 5929
#define VOLOFF Y_SIZE          // vol[n] at out[VOLOFF + n] (temp, inside M region)
#define VSUM (Y_SIZE + 4096)   // volsum at out[VSUM] (temp, inside M region)
#define NPAIR 231              // upper-triangular (i<=j) pairs of 21
#define BLK 512                // contract block threads (8 waves)
#define NPB 8                  // n per contract block
#define GRID_B (NBATCH / NPB)  // 512 blocks
#define EIGT 640               // bisect block: 10 waves (verified 9-section code)

// workspace layout (d_ws): NSLOT partial-S slots + tridiag d/e scratch
#define NSLOT 16
#define SLOT_STRIDE 17792      // NPAIR*NK=17787 padded
#define WS2OFF (NSLOT * SLOT_STRIDE)   // 284672 floats; ws total ~1.14 MB

#define SZ_OMEGA  (NBATCH * NH2 * NH2)   // 1,806,336
#define SZ_PHI    (NBATCH * NK * NC)     // 11,038,720
#define SZ_METRIC (NBATCH * 7 * 7)       // 200,704

// ---------------- compile-time wedge structure constants ----------------
// C[a,b,c] nonzero iff pair_a, pair_b, triple_c partition {0..6}; value = perm
// sign. Exactly 6 (a,b) terms per c. MUST be a constexpr LOCAL in each kernel
// (round-3 finding). C[a,b,c]=C[b,a,c] => S symmetric in (i,j): only i<=j pairs.
// R5: never cap VGPRs below live set (spill -> 5x).
// R12: shfl == ds_bpermute ~120-150cy LDS hop; DPP adds ~5cy.
// R13: single-WAVE tridiag (A in VGPRs, zero barriers) = 138us.
// R14: literal row select + v_pk_fma + gram 77-block: 114us.
// R15 FAILED (+7us): volatile pk_fma pins order; scheduler can't interleave.
// R16: non-volatile asm + oct-sigma + readlane-x1 + sqrt/rcp builtins: 107.6.
// R17 FAILED (375us): fusing 1-wave tridiag into a 640-thread block let the
//   allocator cap VGPR at 84 < ~148 live set -> A spilled to scratch
//   (WRITE_SIZE 0.6KB -> 40KB). R5 law confirmed. NEVER fuse the register-
//   resident tridiag wave into a multi-wave block.
// R18: fusion reverted (64-thr kernel, launch_bounds(64,1), 512-reg budget);
//   PRECOMP kept: next-iter scalars (sigma2/x1/alpha/beta/xha) computed at
//   iteration END from the fresh rc broadcast, overlapped with the 9-row
//   update. Values bit-identical (R17 run passed); isolates PRECOMP's perf.
// R7: LDS strides sharing a factor with the bank-group period -> conflicts.
// R8: 2-barrier staged VALU loop plateaus ~27% VALUBusy -> moved to MFMA (R9).
struct WTab {
  int a[NC][6];
  int b[NC][6];
  int sg[NC][6];
};

constexpr WTab make_wtab() {
  WTab W{};
  int p0[21] = {}, p1[21] = {};
  int idx = 0;
  for (int x = 0; x < 7; ++x)
    for (int y = x + 1; y < 7; ++y) { p0[idx] = x; p1[idx] = y; ++idx; }
  int t0[35] = {}, t1[35] = {}, t2[35] = {};
  idx = 0;
  for (int x = 0; x < 7; ++x)
    for (int y = x + 1; y < 7; ++y)
      for (int z = y + 1; z < 7; ++z) { t0[idx] = x; t1[idx] = y; t2[idx] = z; ++idx; }
  int cnt[35] = {};
  for (int a = 0; a < 21; ++a)
    for (int b = 0; b < 21; ++b) {
      int pa0 = p0[a], pa1 = p1[a], pb0 = p0[b], pb1 = p1[b];
      if (pa0 == pb0 || pa0 == pb1 || pa1 == pb0 || pa1 == pb1) continue;
      bool used[7] = {};
      used[pa0] = true; used[pa1] = true; used[pb0] = true; used[pb1] = true;
      int tr[3] = {}; int k = 0;
      for (int x = 0; x < 7; ++x) if (!used[x]) tr[k++] = x;
      int c = -1;
      for (int cc = 0; cc < 35; ++cc)
        if (t0[cc] == tr[0] && t1[cc] == tr[1] && t2[cc] == tr[2]) { c = cc; break; }
      int perm[7] = {pa0, pa1, pb0, pb1, tr[0], tr[1], tr[2]};
      int inv = 0;
      for (int i = 0; i < 7; ++i)
        for (int j = i + 1; j < 7; ++j)
          if (perm[i] > perm[j]) ++inv;
      W.a[c][cnt[c]] = a; W.b[c][cnt[c]] = b; W.sg[c][cnt[c]] = (inv & 1) ? -1 : 1;
      ++cnt[c];
    }
  return W;
}

__device__ __forceinline__ int trioff(int i) { return 21 * i - (i * (i - 1)) / 2; }

// fp32 -> bf16 (RNE), returns low 16 bits
__device__ __forceinline__ unsigned f2bf(float x) {
  union { float f; unsigned u; } v; v.f = x;
  return ((v.u + 0x7FFFu + ((v.u >> 16) & 1u)) >> 16) & 0xFFFFu;
}

typedef float f32x4 __attribute__((ext_vector_type(4)));
typedef float f32x2 __attribute__((ext_vector_type(2)));
typedef short s16x8 __attribute__((ext_vector_type(8)));

// packed fp32 FMA (VOP3P, gfx90a+): d = a*b + c per 32-bit half. NOT volatile.
__device__ __forceinline__ f32x2 pk_fma(f32x2 a, f32x2 b, f32x2 c) {
  f32x2 d;
  asm("v_pk_fma_f32 %0, %1, %2, %3" : "=v"(d) : "v"(a), "v"(b), "v"(c));
  return d;
}

// ---------------- DPP wave reductions (R12): VALU-latency, no LDS pipe -------
template <int CTRL>
__device__ __forceinline__ float dppadd(float x) {
  union { float f; int i; } u, r;
  u.f = x;
  r.i = __builtin_amdgcn_update_dpp(0, u.i, CTRL, 0xF, 0xF, true);
  return x + r.f;
}
// sum over each aligned group of 8 lanes; result in ALL 8 lanes of the group
__device__ __forceinline__ float oct_sum(float x) {
  x = dppadd<0xB1>(x);    // quad_perm(1,0,3,2)  : + xor1
  x = dppadd<0x4E>(x);    // quad_perm(2,3,0,1)  : + xor2
  x = dppadd<0x141>(x);   // row_half_mirror     : + other quad of 8
  return x;
}
// sum over all 64 lanes; result valid in lane 63
__device__ __forceinline__ float wave_sum(float x) {
  x = dppadd<0xB1>(x);
  x = dppadd<0x4E>(x);
  x = dppadd<0x141>(x);
  x = dppadd<0x140>(x);   // row_mirror
  x = dppadd<0x142>(x);   // row_bcast15
  x = dppadd<0x143>(x);   // row_bcast31
  return x;
}
__device__ __forceinline__ float readlane63(float x) {
  union { float f; int i; } u; u.f = x;
  union { int i; float f; } r;
  r.i = __builtin_amdgcn_readlane(u.i, 63);
  return r.f;
}
__device__ __forceinline__ float readlane0(float x) {
  union { float f; int i; } u; u.f = x;
  union { int i; float f; } r;
  r.i = __builtin_amdgcn_readfirstlane(u.i);
  return r.f;
}
__device__ __forceinline__ float readlaneN(float x, int lane) {
  union { float f; int i; } u; u.f = x;
  union { int i; float f; } r;
  r.i = __builtin_amdgcn_readlane(u.i, lane);
  return r.f;
}

// ---------------- kernel A: vol[n] = sqrt(|det(metric_n)|), + sum ----------------
__global__ __launch_bounds__(256) void vol_kernel(const float* __restrict__ metric,
                                                  float* __restrict__ out) {
  const int n = blockIdx.x * 256 + threadIdx.x;
  double a[7][7];
#pragma unroll
  for (int r = 0; r < 7; ++r)
#pragma unroll
    for (int c = 0; c < 7; ++c) a[r][c] = (double)metric[n * 49 + r * 7 + c];

  double det = 1.0;
#pragma unroll
  for (int k = 0; k < 7; ++k) {
#pragma unroll
    for (int r = k + 1; r < 7; ++r) {
      bool sw = fabs(a[r][k]) > fabs(a[k][k]);
#pragma unroll
      for (int c = k; c < 7; ++c) {
        double u = a[k][c], v = a[r][c];
        a[k][c] = sw ? v : u;
        a[r][c] = sw ? u : v;
      }
    }
    det *= a[k][k];
    double inv = (a[k][k] != 0.0) ? 1.0 / a[k][k] : 0.0;
#pragma unroll
    for (int r = k + 1; r < 7; ++r) {
      double f = a[r][k] * inv;
#pragma unroll
      for (int c = k + 1; c < 7; ++c) a[r][c] -= f * a[k][c];
    }
  }
  float vol = (float)sqrt(fabs(det));
  out[VOLOFF + n] = vol;

  float s = vol;
#pragma unroll
  for (int off = 32; off > 0; off >>= 1) s += __shfl_down(s, off, 64);
  __shared__ float partial[4];
  const int lane = threadIdx.x & 63, wv = threadIdx.x >> 6;
  if (lane == 0) partial[wv] = s;
  __syncthreads();
  if (threadIdx.x == 0)
    atomicAdd(out + VSUM, partial[0] + partial[1] + partial[2] + partial[3]);
}

// ---------------- kernel B: MFMA contract (R13: slot-partial output) ----------
__global__ __launch_bounds__(BLK) void contract_kernel(const float* __restrict__ omega,
                                                       const float* __restrict__ Phi,
                                                       const float* __restrict__ out,
                                                       float* __restrict__ wsS) {
  constexpr WTab W = make_wtab();
  __shared__ __align__(16) short ldsD[256 * 80];  // D rows, stride 80 bf16
  __shared__ __align__(16) short ldsP[80 * 80];   // PW^T rows [q][k], stride 80
  __shared__ __align__(16) float ldsO[NH2 * 28];  // omega rows, stride 28 fp32

  const int t = threadIdx.x;
  const int lane = t & 63;
  const int wv = t >> 6;
  const int quad = lane >> 4;
  const int col = lane & 15;
  const int n0 = blockIdx.x * NPB;

  for (int f = t; f < 256 * 40; f += BLK) ((int*)ldsD)[f] = 0;
  for (int f = t; f < 80 * 40; f += BLK) ((int*)ldsP)[f] = 0;

  const bool roleA = (t < NPAIR);
  const bool roleB = (t >= 256) && (t < 256 + NPAIR);
  int pi = 0, pj = 0;
  {
    const int p = roleA ? t : (roleB ? (t - 256) : 0);
    int i = 0;
    while (i < 20 && trioff(i + 1) <= p) ++i;
    pi = i;
    pj = p - trioff(i) + i;
  }

  float rA = 0.0f, rB[6], rvn;
  {
    const float* om = omega + n0 * 441;
    const float* ph = Phi + n0 * 2695;
    if (t < 441) rA = om[t];
#pragma unroll
    for (int j = 0; j < 6; ++j) {
      const int e = t + j * BLK;
      rB[j] = (e < 2695) ? ph[e] : 0.0f;
    }
    rvn = out[VOLOFF + n0];
  }

  f32x4 acc[2][5];
#pragma unroll
  for (int mi = 0; mi < 2; ++mi)
#pragma unroll
    for (int nt = 0; nt < 5; ++nt) acc[mi][nt] = (f32x4){0.f, 0.f, 0.f, 0.f};

  for (int it = 0; it < NPB; ++it) {
    __syncthreads();

    if (t < 441) ldsO[(t / 21) * 28 + (t % 21)] = rA;
    {
      const float vn = rvn;
#pragma unroll
      for (int j = 0; j < 6; ++j) {
        const int e = t + j * BLK;
        if (e < 2695) {
          const int q = e / 35, c = e % 35;
          ldsP[q * 80 + c] = (short)f2bf(vn * rB[j]);
        }
      }
    }
    __syncthreads();

    if (it + 1 < NPB) {
      const int n1 = n0 + it + 1;
      const float* om2 = omega + n1 * 441;
      const float* ph2 = Phi + n1 * 2695;
      if (t < 441) rA = om2[t];
#pragma unroll
      for (int j = 0; j < 6; ++j) {
        const int e = t + j * BLK;
        if (e < 2695) rB[j] = ph2[e];
      }
      rvn = out[VOLOFF + n1];
    }

    if (roleA || roleB) {
      float wi[21], wj[21];
      const float* oi = ldsO + pi * 28;
      const float* oj = ldsO + pj * 28;
#pragma unroll
      for (int a = 0; a < 20; a += 4) {
        float4 v = *(const float4*)(oi + a);
        wi[a] = v.x; wi[a + 1] = v.y; wi[a + 2] = v.z; wi[a + 3] = v.w;
        float4 u = *(const float4*)(oj + a);
        wj[a] = u.x; wj[a + 1] = u.y; wj[a + 2] = u.z; wj[a + 3] = u.w;
      }
      wi[20] = oi[20]; wj[20] = oj[20];

      if (roleA) {
        float d[18];
#pragma unroll
        for (int c = 0; c < 18; ++c) {
          float dd = 0.0f;
#pragma unroll
          for (int u = 0; u < 6; ++u)
            dd = fmaf((W.sg[c][u] > 0) ? wi[W.a[c][u]] : -wi[W.a[c][u]], wj[W.b[c][u]], dd);
          d[c] = dd;
        }
        int* Drow = (int*)ldsD + t * 40;
#pragma unroll
        for (int k2 = 0; k2 < 9; ++k2)
          Drow[k2] = (int)(f2bf(d[2 * k2]) | (f2bf(d[2 * k2 + 1]) << 16));
      } else {
        float d[17];
#pragma unroll
        for (int c = 18; c < 35; ++c) {
          float dd = 0.0f;
#pragma unroll
          for (int u = 0; u < 6; ++u)
            dd = fmaf((W.sg[c][u] > 0) ? wi[W.a[c][u]] : -wi[W.a[c][u]], wj[W.b[c][u]], dd);
          d[c - 18] = dd;
        }
        int* Drow = (int*)ldsD + (t - 256) * 40;
#pragma unroll
        for (int k2 = 0; k2 < 8; ++k2)
          Drow[9 + k2] = (int)(f2bf(d[2 * k2]) | (f2bf(d[2 * k2 + 1]) << 16));
        Drow[17] = (int)f2bf(d[16]);
      }
    }
    __syncthreads();

#pragma unroll
    for (int s = 0; s < 2; ++s) {
      const int kof = s * 32 + quad * 8;
      s16x8 a0 = *(const s16x8*)(ldsD + ((wv * 2 + 0) * 16 + col) * 80 + kof);
      s16x8 a1 = *(const s16x8*)(ldsD + ((wv * 2 + 1) * 16 + col) * 80 + kof);
      s16x8 b[5];
#pragma unroll
      for (int nt = 0; nt < 5; ++nt)
        b[nt] = *(const s16x8*)(ldsP + (nt * 16 + col) * 80 + kof);
#pragma unroll
      for (int nt = 0; nt < 5; ++nt) {
        acc[0][nt] = __builtin_amdgcn_mfma_f32_16x16x32_bf16(a0, b[nt], acc[0][nt], 0, 0, 0);
        acc[1][nt] = __builtin_amdgcn_mfma_f32_16x16x32_bf16(a1, b[nt], acc[1][nt], 0, 0, 0);
      }
    }
  }

  // R13: scatter into one of NSLOT partial copies (contention /32)
  float* slot = wsS + (size_t)(blockIdx.x & (NSLOT - 1)) * SLOT_STRIDE;
#pragma unroll
  for (int mi = 0; mi < 2; ++mi) {
    const int mt = wv * 2 + mi;
#pragma unroll
    for (int r = 0; r < 4; ++r) {
      const int m = mt * 16 + quad * 4 + r;
      if (m < NPAIR) {
#pragma unroll
        for (int nt = 0; nt < 5; ++nt) {
          const int q = nt * 16 + col;
          if (q < 77) atomicAdd(&slot[m * NK + q], acc[mi][nt][r]);
        }
      }
    }
  }
}

// ---------------- kernel C1: finalize Y from slot partials ----------------
__global__ __launch_bounds__(256) void finalize_y(const float* __restrict__ wsS,
                                                  float* __restrict__ out) {
  const int e = blockIdx.x * 256 + threadIdx.x;
  if (e >= NPAIR * NK) return;
  const int p = e / NK, k = e % NK;
  int i = 0;
  while (i < 20 && trioff(i + 1) <= p) ++i;
  const int j = p - trioff(i) + i;
  float v = 0.0f;
#pragma unroll
  for (int s = 0; s < NSLOT; ++s) v += wsS[(size_t)s * SLOT_STRIDE + p * NK + k];
  v *= 1.0f / out[VSUM];
  out[(i * 21 + j) * NK + k] = v;
  if (j != i) out[(j * 21 + i) * NK + k] = -v;
}

// ---------------- kernel C2: M[k,l] = sum_ij Y_ij,k Y_ij,l (R14) ----------------
__global__ __launch_bounds__(EIGT) void gram_kernel(const float* __restrict__ Y,
                                                    float* __restrict__ Mout) {
  const int k = blockIdx.x;
  const int t = threadIdx.x;
  const int l = t >> 3, s = t & 7;
  float acc = 0.0f;
  if (l < NK) {
    for (int ij = s; ij < NIJ; ij += 8)
      acc = fmaf(Y[ij * NK + k], Y[ij * NK + l], acc);
  }
  acc = oct_sum(acc);
  if (s == 0 && l < NK) Mout[k * NK + l] = acc;
}

// next-iteration scalar precompute (R17/R18): uses the freshly-broadcast rc
// (row KN); O2/B2 literal/semi-literal so rc[O2] stays a register ref.
#define PRECOMP(KN, O2, B2)                                                   \
  do {                                                                        \
    float pt_ = 0.0f;                                                         \
    if (br == 0) {                                                            \
      _Pragma("unroll") for (int c2_ = 0; c2_ < 5; ++c2_) {                   \
        const int gc0_ = 10 * bc + 2 * c2_;                                   \
        const float x0_ = rc[2 * c2_], xv_ = rc[2 * c2_ + 1];                 \
        pt_ += (gc0_ > (KN)) ? x0_ * x0_ : 0.0f;                              \
        pt_ += (gc0_ + 1 > (KN)) ? xv_ * xv_ : 0.0f;                          \
      }                                                                       \
    }                                                                         \
    pt_ = oct_sum(pt_);                                                       \
    sig2c = readlane0(pt_);                                                   \
    const float x1n_ = readlaneN(rc[(O2)], (B2));                             \
    const float sg_ = __builtin_amdgcn_sqrtf(sig2c);                          \
    alpha_c = (x1n_ >= 0.0f) ? -sg_ : sg_;                                    \
    beta_c = __builtin_amdgcn_rcpf(fmaf(-alpha_c, x1n_, sig2c));              \
    xha_c = x1n_ - alpha_c;                                                   \
  } while (0)

// ---------------- kernel D1: single-wave Householder tridiag (R18) ------------
// One wave (64 thr, launch_bounds(64,1) => full 512-VGPR budget, NO spill —
// R17's fusion spilled at 84 regs). A[80x80] in VGPRs as f32x2 col-pairs; lane
// l=(br<<3)|bc owns rows [10br,+10) x col-pairs [5bc,+5). Zero barriers.
// R18: next-iter scalars precomputed at iteration END (overlap w/ update).
// Outputs: ws2[0..79]=diag, ws2[80..155]=offdiag (esh[75]=A[76][75]).
__global__ __launch_bounds__(64, 1) void tridiag_kernel(const float* __restrict__ Min,
                                                        float* __restrict__ ws2) {
  const int l = threadIdx.x;
  const int br = l >> 3, bc = l & 7;
  f32x2 A2[10][5];
#pragma unroll
  for (int r = 0; r < 10; ++r) {
    const int g = 10 * br + r;
#pragma unroll
    for (int c2 = 0; c2 < 5; ++c2) {
      const int gc0 = 10 * bc + 2 * c2;
      A2[r][c2][0] = (g < 77 && gc0 < 77) ? Min[g * 77 + gc0] : 0.0f;
      A2[r][c2][1] = (g < 77 && gc0 + 1 < 77) ? Min[g * 77 + gc0 + 1] : 0.0f;
    }
  }

  // prologue: broadcast row 0 + scalars for k=0
  float rc[10], rr[10];
#pragma unroll
  for (int c2 = 0; c2 < 5; ++c2) {
    rc[2 * c2]     = __shfl(A2[0][c2][0], bc, 64);
    rc[2 * c2 + 1] = __shfl(A2[0][c2][1], bc, 64);
    rr[2 * c2]     = __shfl(A2[0][c2][0], br, 64);
    rr[2 * c2 + 1] = __shfl(A2[0][c2][1], br, 64);
  }
  float sig2c, alpha_c, beta_c, xha_c;
  PRECOMP(0, 1, 0);   // sigma over col>0 of row 0; x1 = A[0][1] (lane 0)

#pragma unroll 1
  for (int kb = 0; kb < 8; ++kb) {
#pragma unroll
    for (int ko = 0; ko < 10; ++ko) {
      if (kb == 7 && ko >= 5) break;           // k stops at 74
      const int k = kb * 10 + ko;
      const int nko = (ko + 1) % 10;           // literal after unroll
      const int nkb = kb + (ko == 9 ? 1 : 0);
      const int nic = nkb * 8 + bc, nir = nkb * 8 + br;
      const int o2 = (ko + 2) % 10;            // col (k+2) local index
      const int b2 = kb + (ko + 2) / 10;       // col (k+2) owner bc

      if (sig2c < 1e-26f) {                    // uniform branch, rare
        if (l == 0) ws2[80 + k] = 0.0f;
#pragma unroll
        for (int c2 = 0; c2 < 5; ++c2) {       // row k+1 unchanged; pipeline
          rc[2 * c2]     = __shfl(A2[nko][c2][0], nic, 64);
          rc[2 * c2 + 1] = __shfl(A2[nko][c2][1], nic, 64);
          rr[2 * c2]     = __shfl(A2[nko][c2][0], nir, 64);
          rr[2 * c2 + 1] = __shfl(A2[nko][c2][1], nir, 64);
        }
        PRECOMP(k + 1, o2, b2);
        continue;
      }
      const float beta = beta_c, xha = xha_c;
      if (l == 0) ws2[80 + k] = alpha_c;

      // v over own cols (from rc) and own rows (from rr) — both local
      f32x2 vc2[5];
      float vr[10];
#pragma unroll
      for (int c2 = 0; c2 < 5; ++c2) {
        const int gc0 = 10 * bc + 2 * c2;
        vc2[c2][0] = (gc0 > k) ? ((gc0 == k + 1) ? xha : rc[2 * c2]) : 0.0f;
        vc2[c2][1] = (gc0 + 1 > k) ? ((gc0 + 1 == k + 1) ? xha : rc[2 * c2 + 1]) : 0.0f;
        const int gr0 = 10 * br + 2 * c2;
        vr[2 * c2] = (gr0 > k) ? ((gr0 == k + 1) ? xha : rr[2 * c2]) : 0.0f;
        vr[2 * c2 + 1] = (gr0 + 1 > k) ? ((gr0 + 1 == k + 1) ? xha : rr[2 * c2 + 1]) : 0.0f;
      }

      // p = beta * A v (packed fma; rows independent)
      float p[10];
#pragma unroll
      for (int r = 0; r < 10; ++r) {
        f32x2 a = (f32x2){0.f, 0.f};
#pragma unroll
        for (int c2 = 0; c2 < 5; ++c2) a = pk_fma(A2[r][c2], vc2[c2], a);
        p[r] = a[0] + a[1];
      }
#pragma unroll
      for (int r = 0; r < 10; ++r) {
        p[r] = oct_sum(p[r]) * beta;
        p[r] = (10 * br + r > k) ? p[r] : 0.0f;
      }

      // prefetch p-by-columns NOW (hides under the K reduction)
      f32x2 pc2[5];
#pragma unroll
      for (int c2 = 0; c2 < 5; ++c2) {
        pc2[c2][0] = __shfl(p[2 * c2], 9 * bc, 64);
        pc2[c2][1] = __shfl(p[2 * c2 + 1], 9 * bc, 64);
      }

      // K = p . v (rows counted once: bc==0 lanes)
      float kp = 0.0f;
      if (bc == 0) {
#pragma unroll
        for (int r = 0; r < 10; ++r) kp = fmaf(p[r], vr[r], kp);
      }
      kp = wave_sum(kp);
      const float hb = 0.5f * beta * readlane63(kp);

      // w by rows (local); wc by cols LOCAL from prefetched pc
      float w[10];
#pragma unroll
      for (int r = 0; r < 10; ++r) w[r] = fmaf(-hb, vr[r], p[r]);
      const f32x2 mhb = (f32x2){-hb, -hb};
      f32x2 wc2[5];
#pragma unroll
      for (int c2 = 0; c2 < 5; ++c2) wc2[c2] = pk_fma(mhb, vc2[c2], pc2[c2]);

      // rank-2 update: pivot row nko FIRST, issue next broadcast, then rest
      {
        const f32x2 nv = (f32x2){-vr[nko], -vr[nko]};
        const f32x2 nw = (f32x2){-w[nko], -w[nko]};
#pragma unroll
        for (int c2 = 0; c2 < 5; ++c2)
          A2[nko][c2] = pk_fma(nv, wc2[c2], pk_fma(nw, vc2[c2], A2[nko][c2]));
      }
#pragma unroll
      for (int c2 = 0; c2 < 5; ++c2) {
        rc[2 * c2]     = __shfl(A2[nko][c2][0], nic, 64);
        rc[2 * c2 + 1] = __shfl(A2[nko][c2][1], nic, 64);
        rr[2 * c2]     = __shfl(A2[nko][c2][0], nir, 64);
        rr[2 * c2 + 1] = __shfl(A2[nko][c2][1], nir, 64);
      }
#pragma unroll
      for (int r = 0; r < 10; ++r) {
        if (r == nko) continue;
        const f32x2 nv = (f32x2){-vr[r], -vr[r]};
        const f32x2 nw = (f32x2){-w[r], -w[r]};
#pragma unroll
        for (int c2 = 0; c2 < 5; ++c2)
          A2[r][c2] = pk_fma(nv, wc2[c2], pk_fma(nw, vc2[c2], A2[r][c2]));
      }

      // next-iteration scalars, overlapped with the update issue above
      PRECOMP(k + 1, o2, b2);
    }
  }

  // gather tridiagonal: diag from lanes br==bc, last offdiag from lane 63
  if (br == bc) {
#pragma unroll
    for (int e = 0; e < 10; ++e)
      ws2[10 * br + e] = (e & 1) ? A2[e][e / 2][1] : A2[e][e / 2][0];
  }
  if (l == 63) ws2[80 + 75] = A2[6][2][1];     // A[76][75]
}

// ---------------- kernel D2: bisection (verified 9-section, 640 thr) ----------
__global__ __launch_bounds__(EIGT) void bisect_kernel(const float* __restrict__ ws2,
                                                      float* __restrict__ eout) {
  __shared__ float dsh[80], esh[80], e2sh[80];
  __shared__ float red[10], red2[10];
  const int t = threadIdx.x;
  const int lane = t & 63, wv = t >> 6;
  if (t < 80) {
    dsh[t] = ws2[t];
    esh[t] = (t < 76) ? ws2[80 + t] : 0.0f;
  }
  __syncthreads();
  if (t < 76) e2sh[t] = esh[t] * esh[t];

  // Gershgorin bounds (parallel reduce)
  float lo_ = 1e30f, hi_ = -1e30f;
  if (t < 77) {
    const float r = ((t > 0) ? fabsf(esh[t - 1]) : 0.0f) +
                    ((t < 76) ? fabsf(esh[t]) : 0.0f);
    lo_ = dsh[t] - r;
    hi_ = dsh[t] + r;
  }
#pragma unroll
  for (int off = 1; off < 64; off <<= 1) {
    lo_ = fminf(lo_, __shfl_xor(lo_, off, 64));
    hi_ = fmaxf(hi_, __shfl_xor(hi_, off, 64));
  }
  if (lane == 0) { red[wv] = lo_; red2[wv] = hi_; }
  __syncthreads();                          // also fences e2sh/dsh
  lo_ = red[0]; hi_ = red2[0];
#pragma unroll
  for (int u = 1; u < 10; ++u) { lo_ = fminf(lo_, red[u]); hi_ = fmaxf(hi_, red2[u]); }
  const float span = hi_ - lo_;
  const float glo = lo_ - 0.001f * span - 1e-6f;
  const float ghi = hi_ + 0.001f * span + 1e-6f;

  // 9-section search via Sturm count: 8 probe lanes per eigenvalue, 13 rounds
  {
    const int e = t >> 3;        // eigenvalue index 0..79 (77..79 inactive)
    const int s = t & 7;         // probe lane within oct
    const int g = (t & 63) >> 3; // oct group within wave
    float lo = glo, hi = ghi;
    for (int r = 0; r < 13; ++r) {
      const float step = (hi - lo) * (1.0f / 9.0f);
      const float x = fmaf(step, (float)(s + 1), lo);
      float q = dsh[0] - x;
      int cnt = (q < 0.0f);
#pragma unroll 4
      for (int i = 1; i < 77; ++i) {
        q = (fabsf(q) < 1e-30f) ? -1e-30f : q;
        q = dsh[i] - x - e2sh[i - 1] * __builtin_amdgcn_rcpf(q);
        cnt += (q < 0.0f);
      }
      const unsigned long long mask = __ballot(cnt > e);
      const int b = (int)((mask >> (g * 8)) & 0xFFull);
      const int z = b ? __builtin_ctz(b) : 8;   // probes with cnt<=e
      const float nlo = fmaf(step, (float)z, lo);
      hi = (z == 8) ? hi : fmaf(step, (float)(z + 1), lo);
      lo = nlo;
    }
    if (s == 0 && e < 77) eout[76 - e] = 0.5f * (lo + hi);  // descending
  }
}

// ---------------- launch ----------------
extern "C" void kernel_launch(void* const* d_in, const int* in_sizes, int n_in,
                              void* d_out, int out_size, void* d_ws, size_t ws_size,
                              hipStream_t stream) {
  const float* omega  = (const float*)d_in[0];
  const float* Phi    = (const float*)d_in[1];
  const float* metric = (const float*)d_in[2];
  for (int q = 0; q < n_in && q < 3; ++q) {
    if (in_sizes[q] == SZ_OMEGA)       omega  = (const float*)d_in[q];
    else if (in_sizes[q] == SZ_PHI)    Phi    = (const float*)d_in[q];
    else if (in_sizes[q] == SZ_METRIC) metric = (const float*)d_in[q];
  }

  float* out = (float*)d_out;
  float* ws  = (float*)d_ws;   // needs (WS2OFF + 160)*4 ~ 1.14 MB

  // out[0 .. Y_SIZE)           : finalized Y
  // out[VOLOFF .. VOLOFF+4096) : vol[n] (temp, overwritten by gram's M)
  // out[VSUM]                  : volsum (temp, overwritten by gram's M)
  // ws[0 .. WS2OFF)            : NSLOT partial-S slots
  // ws[WS2OFF .. +160)         : tridiagonal d/e scratch
  hipMemsetAsync(d_out, 0, (size_t)out_size * sizeof(float), stream);
  hipMemsetAsync(d_ws, 0, (size_t)WS2OFF * sizeof(float), stream);

  hipLaunchKernelGGL(vol_kernel, dim3(NBATCH / 256), dim3(256), 0, stream, metric, out);
  hipLaunchKernelGGL(contract_kernel, dim3(GRID_B), dim3(BLK), 0, stream,
                     omega, Phi, out, ws);
  hipLaunchKernelGGL(finalize_y, dim3((NPAIR * NK + 255) / 256), dim3(256), 0, stream,
                     ws, out);
  hipLaunchKernelGGL(gram_kernel, dim3(NK), dim3(EIGT), 0, stream,
                     out, out + Y_SIZE);
  hipLaunchKernelGGL(tridiag_kernel, dim3(1), dim3(64), 0, stream,
                     out + Y_SIZE, ws + WS2OFF);
  hipLaunchKernelGGL(bisect_kernel, dim3(1), dim3(EIGT), 0, stream,
                     ws + WS2OFF, out + Y_SIZE + M_SIZE);
}

// Round 9
// 344.266 us; speedup vs baseline: 1.6205x; 1.0122x over previous
//
#include <hip/hip_runtime.h>
#include <math.h>

#define NBATCH 4096
#define NH2 21
#define NK 77
#define NC 35
#define NIJ 441
#define Y_SIZE 33957
#define M_SIZE 5929
#define VOLOFF Y_SIZE          // vol[n] at out[VOLOFF + n] (temp, inside M region)
#define VSUM (Y_SIZE + 4096)   // volsum at out[VSUM] (temp, inside M region)
#define NPAIR 231              // upper-triangular (i<=j) pairs of 21
#define BLK 512                // contract block threads (8 waves)
#define NPB 8                  // n per contract block
#define GRID_B (NBATCH / NPB)  // 512 blocks
#define EIGT 640               // bisect block: 10 waves (verified 9-section code)
#define LDS_K 72               // R19: D/P row stride in shorts (was 80): 36
                               // words -> rows 8 apart alias -> 2-way = free
                               // (m136); 80 = 40 words -> 4-way = 1.58x.

// workspace layout (d_ws): NSLOT partial-S slots + tridiag d/e scratch
#define NSLOT 16
#define SLOT_STRIDE 17792      // NPAIR*NK=17787 padded
#define WS2OFF (NSLOT * SLOT_STRIDE)   // 284672 floats; ws total ~1.14 MB

#define SZ_OMEGA  (NBATCH * NH2 * NH2)   // 1,806,336
#define SZ_PHI    (NBATCH * NK * NC)     // 11,038,720
#define SZ_METRIC (NBATCH * 7 * 7)       // 200,704

// ---------------- compile-time wedge structure constants ----------------
// C[a,b,c] nonzero iff pair_a, pair_b, triple_c partition {0..6}; value = perm
// sign. Exactly 6 (a,b) terms per c. MUST be a constexpr LOCAL in each kernel
// (round-3 finding). C[a,b,c]=C[b,a,c] => S symmetric in (i,j): only i<=j pairs.
// R5: never cap VGPRs below live set (spill -> 5x).
// R12: shfl == ds_bpermute ~120-150cy LDS hop; DPP adds ~5cy.
// R13: single-WAVE tridiag (A in VGPRs, zero barriers) = 138us.
// R14: literal row select + v_pk_fma + gram 77-block: 114us.
// R15 FAILED (+7us): volatile pk_fma pins order; scheduler can't interleave.
// R16: non-volatile asm + oct-sigma + readlane-x1 + sqrt/rcp builtins: 107.6us.
//   This tridiag schedule is PINNED — do not restructure (see R15/R17/R18).
// R17 FAILED (375us): fusing tridiag into a 640-thr block capped VGPR at 84 <
//   148 live -> scratch spill (R5 confirmed).
// R18 FAILED (200us): PRECOMP (tail-hoisted next-iter scalars) doubled stall
//   with identical issue count (VALUBusy*t const, duty 48%->27%): the 10x
//   unrolled body + longer live ranges broke the R16 schedule. Reverted.
// R19: contract ldsD/ldsP stride 80->72 shorts (bank 4-way->2-way free, LDS
//   56.3->50.7KB, 3 blocks/CU capacity).
// R7: LDS strides sharing a factor with the bank-group period -> conflicts.
// R8: 2-barrier staged VALU loop plateaus ~27% VALUBusy -> moved to MFMA (R9).
struct WTab {
  int a[NC][6];
  int b[NC][6];
  int sg[NC][6];
};

constexpr WTab make_wtab() {
  WTab W{};
  int p0[21] = {}, p1[21] = {};
  int idx = 0;
  for (int x = 0; x < 7; ++x)
    for (int y = x + 1; y < 7; ++y) { p0[idx] = x; p1[idx] = y; ++idx; }
  int t0[35] = {}, t1[35] = {}, t2[35] = {};
  idx = 0;
  for (int x = 0; x < 7; ++x)
    for (int y = x + 1; y < 7; ++y)
      for (int z = y + 1; z < 7; ++z) { t0[idx] = x; t1[idx] = y; t2[idx] = z; ++idx; }
  int cnt[35] = {};
  for (int a = 0; a < 21; ++a)
    for (int b = 0; b < 21; ++b) {
      int pa0 = p0[a], pa1 = p1[a], pb0 = p0[b], pb1 = p1[b];
      if (pa0 == pb0 || pa0 == pb1 || pa1 == pb0 || pa1 == pb1) continue;
      bool used[7] = {};
      used[pa0] = true; used[pa1] = true; used[pb0] = true; used[pb1] = true;
      int tr[3] = {}; int k = 0;
      for (int x = 0; x < 7; ++x) if (!used[x]) tr[k++] = x;
      int c = -1;
      for (int cc = 0; cc < 35; ++cc)
        if (t0[cc] == tr[0] && t1[cc] == tr[1] && t2[cc] == tr[2]) { c = cc; break; }
      int perm[7] = {pa0, pa1, pb0, pb1, tr[0], tr[1], tr[2]};
      int inv = 0;
      for (int i = 0; i < 7; ++i)
        for (int j = i + 1; j < 7; ++j)
          if (perm[i] > perm[j]) ++inv;
      W.a[c][cnt[c]] = a; W.b[c][cnt[c]] = b; W.sg[c][cnt[c]] = (inv & 1) ? -1 : 1;
      ++cnt[c];
    }
  return W;
}

__device__ __forceinline__ int trioff(int i) { return 21 * i - (i * (i - 1)) / 2; }

// fp32 -> bf16 (RNE), returns low 16 bits
__device__ __forceinline__ unsigned f2bf(float x) {
  union { float f; unsigned u; } v; v.f = x;
  return ((v.u + 0x7FFFu + ((v.u >> 16) & 1u)) >> 16) & 0xFFFFu;
}

typedef float f32x4 __attribute__((ext_vector_type(4)));
typedef float f32x2 __attribute__((ext_vector_type(2)));
typedef short s16x8 __attribute__((ext_vector_type(8)));

// packed fp32 FMA (VOP3P, gfx90a+): d = a*b + c per 32-bit half. NOT volatile.
__device__ __forceinline__ f32x2 pk_fma(f32x2 a, f32x2 b, f32x2 c) {
  f32x2 d;
  asm("v_pk_fma_f32 %0, %1, %2, %3" : "=v"(d) : "v"(a), "v"(b), "v"(c));
  return d;
}

// ---------------- DPP wave reductions (R12): VALU-latency, no LDS pipe -------
template <int CTRL>
__device__ __forceinline__ float dppadd(float x) {
  union { float f; int i; } u, r;
  u.f = x;
  r.i = __builtin_amdgcn_update_dpp(0, u.i, CTRL, 0xF, 0xF, true);
  return x + r.f;
}
// sum over each aligned group of 8 lanes; result in ALL 8 lanes of the group
__device__ __forceinline__ float oct_sum(float x) {
  x = dppadd<0xB1>(x);    // quad_perm(1,0,3,2)  : + xor1
  x = dppadd<0x4E>(x);    // quad_perm(2,3,0,1)  : + xor2
  x = dppadd<0x141>(x);   // row_half_mirror     : + other quad of 8
  return x;
}
// sum over all 64 lanes; result valid in lane 63
__device__ __forceinline__ float wave_sum(float x) {
  x = dppadd<0xB1>(x);
  x = dppadd<0x4E>(x);
  x = dppadd<0x141>(x);
  x = dppadd<0x140>(x);   // row_mirror
  x = dppadd<0x142>(x);   // row_bcast15
  x = dppadd<0x143>(x);   // row_bcast31
  return x;
}
__device__ __forceinline__ float readlane63(float x) {
  union { float f; int i; } u; u.f = x;
  union { int i; float f; } r;
  r.i = __builtin_amdgcn_readlane(u.i, 63);
  return r.f;
}
__device__ __forceinline__ float readlane0(float x) {
  union { float f; int i; } u; u.f = x;
  union { int i; float f; } r;
  r.i = __builtin_amdgcn_readfirstlane(u.i);
  return r.f;
}
__device__ __forceinline__ float readlaneN(float x, int lane) {
  union { float f; int i; } u; u.f = x;
  union { int i; float f; } r;
  r.i = __builtin_amdgcn_readlane(u.i, lane);
  return r.f;
}

// ---------------- kernel A: vol[n] = sqrt(|det(metric_n)|), + sum ----------------
__global__ __launch_bounds__(256) void vol_kernel(const float* __restrict__ metric,
                                                  float* __restrict__ out) {
  const int n = blockIdx.x * 256 + threadIdx.x;
  double a[7][7];
#pragma unroll
  for (int r = 0; r < 7; ++r)
#pragma unroll
    for (int c = 0; c < 7; ++c) a[r][c] = (double)metric[n * 49 + r * 7 + c];

  double det = 1.0;
#pragma unroll
  for (int k = 0; k < 7; ++k) {
#pragma unroll
    for (int r = k + 1; r < 7; ++r) {
      bool sw = fabs(a[r][k]) > fabs(a[k][k]);
#pragma unroll
      for (int c = k; c < 7; ++c) {
        double u = a[k][c], v = a[r][c];
        a[k][c] = sw ? v : u;
        a[r][c] = sw ? u : v;
      }
    }
    det *= a[k][k];
    double inv = (a[k][k] != 0.0) ? 1.0 / a[k][k] : 0.0;
#pragma unroll
    for (int r = k + 1; r < 7; ++r) {
      double f = a[r][k] * inv;
#pragma unroll
      for (int c = k + 1; c < 7; ++c) a[r][c] -= f * a[k][c];
    }
  }
  float vol = (float)sqrt(fabs(det));
  out[VOLOFF + n] = vol;

  float s = vol;
#pragma unroll
  for (int off = 32; off > 0; off >>= 1) s += __shfl_down(s, off, 64);
  __shared__ float partial[4];
  const int lane = threadIdx.x & 63, wv = threadIdx.x >> 6;
  if (lane == 0) partial[wv] = s;
  __syncthreads();
  if (threadIdx.x == 0)
    atomicAdd(out + VSUM, partial[0] + partial[1] + partial[2] + partial[3]);
}

// ---------------- kernel B: MFMA contract (R19: stride-72 LDS) ----------------
__global__ __launch_bounds__(BLK) void contract_kernel(const float* __restrict__ omega,
                                                       const float* __restrict__ Phi,
                                                       const float* __restrict__ out,
                                                       float* __restrict__ wsS) {
  constexpr WTab W = make_wtab();
  __shared__ __align__(16) short ldsD[256 * LDS_K];  // D rows, stride 72 bf16
  __shared__ __align__(16) short ldsP[80 * LDS_K];   // PW^T rows [q][k]
  __shared__ __align__(16) float ldsO[NH2 * 28];     // omega rows, stride 28 fp32

  const int t = threadIdx.x;
  const int lane = t & 63;
  const int wv = t >> 6;
  const int quad = lane >> 4;
  const int col = lane & 15;
  const int n0 = blockIdx.x * NPB;

  for (int f = t; f < 256 * (LDS_K / 2); f += BLK) ((int*)ldsD)[f] = 0;
  for (int f = t; f < 80 * (LDS_K / 2); f += BLK) ((int*)ldsP)[f] = 0;

  const bool roleA = (t < NPAIR);
  const bool roleB = (t >= 256) && (t < 256 + NPAIR);
  int pi = 0, pj = 0;
  {
    const int p = roleA ? t : (roleB ? (t - 256) : 0);
    int i = 0;
    while (i < 20 && trioff(i + 1) <= p) ++i;
    pi = i;
    pj = p - trioff(i) + i;
  }

  float rA = 0.0f, rB[6], rvn;
  {
    const float* om = omega + n0 * 441;
    const float* ph = Phi + n0 * 2695;
    if (t < 441) rA = om[t];
#pragma unroll
    for (int j = 0; j < 6; ++j) {
      const int e = t + j * BLK;
      rB[j] = (e < 2695) ? ph[e] : 0.0f;
    }
    rvn = out[VOLOFF + n0];
  }

  f32x4 acc[2][5];
#pragma unroll
  for (int mi = 0; mi < 2; ++mi)
#pragma unroll
    for (int nt = 0; nt < 5; ++nt) acc[mi][nt] = (f32x4){0.f, 0.f, 0.f, 0.f};

  for (int it = 0; it < NPB; ++it) {
    __syncthreads();

    if (t < 441) ldsO[(t / 21) * 28 + (t % 21)] = rA;
    {
      const float vn = rvn;
#pragma unroll
      for (int j = 0; j < 6; ++j) {
        const int e = t + j * BLK;
        if (e < 2695) {
          const int q = e / 35, c = e % 35;
          ldsP[q * LDS_K + c] = (short)f2bf(vn * rB[j]);
        }
      }
    }
    __syncthreads();

    if (it + 1 < NPB) {
      const int n1 = n0 + it + 1;
      const float* om2 = omega + n1 * 441;
      const float* ph2 = Phi + n1 * 2695;
      if (t < 441) rA = om2[t];
#pragma unroll
      for (int j = 0; j < 6; ++j) {
        const int e = t + j * BLK;
        if (e < 2695) rB[j] = ph2[e];
      }
      rvn = out[VOLOFF + n1];
    }

    if (roleA || roleB) {
      float wi[21], wj[21];
      const float* oi = ldsO + pi * 28;
      const float* oj = ldsO + pj * 28;
#pragma unroll
      for (int a = 0; a < 20; a += 4) {
        float4 v = *(const float4*)(oi + a);
        wi[a] = v.x; wi[a + 1] = v.y; wi[a + 2] = v.z; wi[a + 3] = v.w;
        float4 u = *(const float4*)(oj + a);
        wj[a] = u.x; wj[a + 1] = u.y; wj[a + 2] = u.z; wj[a + 3] = u.w;
      }
      wi[20] = oi[20]; wj[20] = oj[20];

      if (roleA) {
        float d[18];
#pragma unroll
        for (int c = 0; c < 18; ++c) {
          float dd = 0.0f;
#pragma unroll
          for (int u = 0; u < 6; ++u)
            dd = fmaf((W.sg[c][u] > 0) ? wi[W.a[c][u]] : -wi[W.a[c][u]], wj[W.b[c][u]], dd);
          d[c] = dd;
        }
        int* Drow = (int*)ldsD + t * (LDS_K / 2);
#pragma unroll
        for (int k2 = 0; k2 < 9; ++k2)
          Drow[k2] = (int)(f2bf(d[2 * k2]) | (f2bf(d[2 * k2 + 1]) << 16));
      } else {
        float d[17];
#pragma unroll
        for (int c = 18; c < 35; ++c) {
          float dd = 0.0f;
#pragma unroll
          for (int u = 0; u < 6; ++u)
            dd = fmaf((W.sg[c][u] > 0) ? wi[W.a[c][u]] : -wi[W.a[c][u]], wj[W.b[c][u]], dd);
          d[c - 18] = dd;
        }
        int* Drow = (int*)ldsD + (t - 256) * (LDS_K / 2);
#pragma unroll
        for (int k2 = 0; k2 < 8; ++k2)
          Drow[9 + k2] = (int)(f2bf(d[2 * k2]) | (f2bf(d[2 * k2 + 1]) << 16));
        Drow[17] = (int)f2bf(d[16]);
      }
    }
    __syncthreads();

#pragma unroll
    for (int s = 0; s < 2; ++s) {
      const int kof = s * 32 + quad * 8;
      s16x8 a0 = *(const s16x8*)(ldsD + ((wv * 2 + 0) * 16 + col) * LDS_K + kof);
      s16x8 a1 = *(const s16x8*)(ldsD + ((wv * 2 + 1) * 16 + col) * LDS_K + kof);
      s16x8 b[5];
#pragma unroll
      for (int nt = 0; nt < 5; ++nt)
        b[nt] = *(const s16x8*)(ldsP + (nt * 16 + col) * LDS_K + kof);
#pragma unroll
      for (int nt = 0; nt < 5; ++nt) {
        acc[0][nt] = __builtin_amdgcn_mfma_f32_16x16x32_bf16(a0, b[nt], acc[0][nt], 0, 0, 0);
        acc[1][nt] = __builtin_amdgcn_mfma_f32_16x16x32_bf16(a1, b[nt], acc[1][nt], 0, 0, 0);
      }
    }
  }

  // R13: scatter into one of NSLOT partial copies (contention /32)
  float* slot = wsS + (size_t)(blockIdx.x & (NSLOT - 1)) * SLOT_STRIDE;
#pragma unroll
  for (int mi = 0; mi < 2; ++mi) {
    const int mt = wv * 2 + mi;
#pragma unroll
    for (int r = 0; r < 4; ++r) {
      const int m = mt * 16 + quad * 4 + r;
      if (m < NPAIR) {
#pragma unroll
        for (int nt = 0; nt < 5; ++nt) {
          const int q = nt * 16 + col;
          if (q < 77) atomicAdd(&slot[m * NK + q], acc[mi][nt][r]);
        }
      }
    }
  }
}

// ---------------- kernel C1: finalize Y from slot partials ----------------
__global__ __launch_bounds__(256) void finalize_y(const float* __restrict__ wsS,
                                                  float* __restrict__ out) {
  const int e = blockIdx.x * 256 + threadIdx.x;
  if (e >= NPAIR * NK) return;
  const int p = e / NK, k = e % NK;
  int i = 0;
  while (i < 20 && trioff(i + 1) <= p) ++i;
  const int j = p - trioff(i) + i;
  float v = 0.0f;
#pragma unroll
  for (int s = 0; s < NSLOT; ++s) v += wsS[(size_t)s * SLOT_STRIDE + p * NK + k];
  v *= 1.0f / out[VSUM];
  out[(i * 21 + j) * NK + k] = v;
  if (j != i) out[(j * 21 + i) * NK + k] = -v;
}

// ---------------- kernel C2: M[k,l] = sum_ij Y_ij,k Y_ij,l (R14) ----------------
__global__ __launch_bounds__(EIGT) void gram_kernel(const float* __restrict__ Y,
                                                    float* __restrict__ Mout) {
  const int k = blockIdx.x;
  const int t = threadIdx.x;
  const int l = t >> 3, s = t & 7;
  float acc = 0.0f;
  if (l < NK) {
    for (int ij = s; ij < NIJ; ij += 8)
      acc = fmaf(Y[ij * NK + k], Y[ij * NK + l], acc);
  }
  acc = oct_sum(acc);
  if (s == 0 && l < NK) Mout[k * NK + l] = acc;
}

// ---------------- kernel D1: single-wave Householder tridiag (R16, PINNED) ----
// One wave, A[80x80] in VGPRs as f32x2 col-pairs: lane l=(br<<3)|bc owns rows
// [10br,+10) x col-pairs [5bc,+5). Zero barriers, zero LDS. Measured 107.6us;
// R15/R17/R18 restructures all regressed — do not modify the schedule.
__global__ __launch_bounds__(64, 1) void tridiag_kernel(const float* __restrict__ Min,
                                                        float* __restrict__ ws2) {
  const int l = threadIdx.x;
  const int br = l >> 3, bc = l & 7;
  f32x2 A2[10][5];
#pragma unroll
  for (int r = 0; r < 10; ++r) {
    const int g = 10 * br + r;
#pragma unroll
    for (int c2 = 0; c2 < 5; ++c2) {
      const int gc0 = 10 * bc + 2 * c2;
      A2[r][c2][0] = (g < 77 && gc0 < 77) ? Min[g * 77 + gc0] : 0.0f;
      A2[r][c2][1] = (g < 77 && gc0 + 1 < 77) ? Min[g * 77 + gc0 + 1] : 0.0f;
    }
  }

  // prologue: broadcast row 0 (col-chunks from lane bc, row-chunks from lane br)
  float rc[10], rr[10];
#pragma unroll
  for (int c2 = 0; c2 < 5; ++c2) {
    rc[2 * c2]     = __shfl(A2[0][c2][0], bc, 64);
    rc[2 * c2 + 1] = __shfl(A2[0][c2][1], bc, 64);
    rr[2 * c2]     = __shfl(A2[0][c2][0], br, 64);
    rr[2 * c2 + 1] = __shfl(A2[0][c2][1], br, 64);
  }

#pragma unroll 1
  for (int kb = 0; kb < 8; ++kb) {
#pragma unroll
    for (int ko = 0; ko < 10; ++ko) {
      if (kb == 7 && ko >= 5) break;           // k stops at 74
      const int k = kb * 10 + ko;
      const int nko = (ko + 1) % 10;           // literal after unroll
      const int nkb = kb + (ko == 9 ? 1 : 0);
      const int nic = nkb * 8 + bc, nir = nkb * 8 + br;

      // sigma2 partials (br==0 lanes = oct 0) -> 3-hop oct_sum + readfirstlane
      float part = 0.0f;
      if (br == 0) {
#pragma unroll
        for (int c2 = 0; c2 < 5; ++c2) {
          const int gc0 = 10 * bc + 2 * c2;
          const float x0 = rc[2 * c2], xv = rc[2 * c2 + 1];
          part += (gc0 > k) ? x0 * x0 : 0.0f;
          part += (gc0 + 1 > k) ? xv * xv : 0.0f;
        }
      }
      part = oct_sum(part);
      const float sigma2 = readlane0(part);
      if (sigma2 < 1e-26f) {                   // uniform branch, rare
        if (l == 0) ws2[80 + k] = 0.0f;
#pragma unroll
        for (int c2 = 0; c2 < 5; ++c2) {       // still pipeline next bcast
          rc[2 * c2]     = __shfl(A2[nko][c2][0], nic, 64);
          rc[2 * c2 + 1] = __shfl(A2[nko][c2][1], nic, 64);
          rr[2 * c2]     = __shfl(A2[nko][c2][0], nir, 64);
          rr[2 * c2 + 1] = __shfl(A2[nko][c2][1], nir, 64);
        }
        continue;
      }
      // x1 = A[k][k+1]: col k+1 sits in rc[nko] of lanes with bc==nkb
      const float x1 = readlaneN(rc[nko], nkb);
      const float sigma = __builtin_amdgcn_sqrtf(sigma2);
      const float alpha = (x1 >= 0.0f) ? -sigma : sigma;
      const float beta = __builtin_amdgcn_rcpf(fmaf(-alpha, x1, sigma2));
      const float xha = x1 - alpha;
      if (l == 0) ws2[80 + k] = alpha;

      // v over own cols (from rc) and own rows (from rr) — both local
      f32x2 vc2[5];
      float vr[10];
#pragma unroll
      for (int c2 = 0; c2 < 5; ++c2) {
        const int gc0 = 10 * bc + 2 * c2;
        vc2[c2][0] = (gc0 > k) ? ((gc0 == k + 1) ? xha : rc[2 * c2]) : 0.0f;
        vc2[c2][1] = (gc0 + 1 > k) ? ((gc0 + 1 == k + 1) ? xha : rc[2 * c2 + 1]) : 0.0f;
        const int gr0 = 10 * br + 2 * c2;
        vr[2 * c2] = (gr0 > k) ? ((gr0 == k + 1) ? xha : rr[2 * c2]) : 0.0f;
        vr[2 * c2 + 1] = (gr0 + 1 > k) ? ((gr0 + 1 == k + 1) ? xha : rr[2 * c2 + 1]) : 0.0f;
      }

      // p = beta * A v (packed fma; rows independent)
      float p[10];
#pragma unroll
      for (int r = 0; r < 10; ++r) {
        f32x2 a = (f32x2){0.f, 0.f};
#pragma unroll
        for (int c2 = 0; c2 < 5; ++c2) a = pk_fma(A2[r][c2], vc2[c2], a);
        p[r] = a[0] + a[1];
      }
#pragma unroll
      for (int r = 0; r < 10; ++r) {
        p[r] = oct_sum(p[r]) * beta;
        p[r] = (10 * br + r > k) ? p[r] : 0.0f;
      }

      // prefetch p-by-columns NOW (hides under the K reduction)
      f32x2 pc2[5];
#pragma unroll
      for (int c2 = 0; c2 < 5; ++c2) {
        pc2[c2][0] = __shfl(p[2 * c2], 9 * bc, 64);
        pc2[c2][1] = __shfl(p[2 * c2 + 1], 9 * bc, 64);
      }

      // K = p . v (rows counted once: bc==0 lanes)
      float kp = 0.0f;
      if (bc == 0) {
#pragma unroll
        for (int r = 0; r < 10; ++r) kp = fmaf(p[r], vr[r], kp);
      }
      kp = wave_sum(kp);
      const float hb = 0.5f * beta * readlane63(kp);

      // w by rows (local); wc by cols LOCAL from prefetched pc
      float w[10];
#pragma unroll
      for (int r = 0; r < 10; ++r) w[r] = fmaf(-hb, vr[r], p[r]);
      const f32x2 mhb = (f32x2){-hb, -hb};
      f32x2 wc2[5];
#pragma unroll
      for (int c2 = 0; c2 < 5; ++c2) wc2[c2] = pk_fma(mhb, vc2[c2], pc2[c2]);

      // rank-2 update: pivot row nko FIRST, issue next broadcast, then rest
      {
        const f32x2 nv = (f32x2){-vr[nko], -vr[nko]};
        const f32x2 nw = (f32x2){-w[nko], -w[nko]};
#pragma unroll
        for (int c2 = 0; c2 < 5; ++c2)
          A2[nko][c2] = pk_fma(nv, wc2[c2], pk_fma(nw, vc2[c2], A2[nko][c2]));
      }
#pragma unroll
      for (int c2 = 0; c2 < 5; ++c2) {
        rc[2 * c2]     = __shfl(A2[nko][c2][0], nic, 64);
        rc[2 * c2 + 1] = __shfl(A2[nko][c2][1], nic, 64);
        rr[2 * c2]     = __shfl(A2[nko][c2][0], nir, 64);
        rr[2 * c2 + 1] = __shfl(A2[nko][c2][1], nir, 64);
      }
#pragma unroll
      for (int r = 0; r < 10; ++r) {
        if (r == nko) continue;
        const f32x2 nv = (f32x2){-vr[r], -vr[r]};
        const f32x2 nw = (f32x2){-w[r], -w[r]};
#pragma unroll
        for (int c2 = 0; c2 < 5; ++c2)
          A2[r][c2] = pk_fma(nv, wc2[c2], pk_fma(nw, vc2[c2], A2[r][c2]));
      }
    }
  }

  // gather tridiagonal: diag from lanes br==bc, last offdiag from lane 63
  if (br == bc) {
#pragma unroll
    for (int e = 0; e < 10; ++e)
      ws2[10 * br + e] = (e & 1) ? A2[e][e / 2][1] : A2[e][e / 2][0];
  }
  if (l == 63) ws2[80 + 75] = A2[6][2][1];     // A[76][75]
}

// ---------------- kernel D2: bisection (verified 9-section, 640 thr) ----------
__global__ __launch_bounds__(EIGT) void bisect_kernel(const float* __restrict__ ws2,
                                                      float* __restrict__ eout) {
  __shared__ float dsh[80], esh[80], e2sh[80];
  __shared__ float red[10], red2[10];
  const int t = threadIdx.x;
  const int lane = t & 63, wv = t >> 6;
  if (t < 80) {
    dsh[t] = ws2[t];
    esh[t] = (t < 76) ? ws2[80 + t] : 0.0f;
  }
  __syncthreads();
  if (t < 76) e2sh[t] = esh[t] * esh[t];

  // Gershgorin bounds (parallel reduce)
  float lo_ = 1e30f, hi_ = -1e30f;
  if (t < 77) {
    const float r = ((t > 0) ? fabsf(esh[t - 1]) : 0.0f) +
                    ((t < 76) ? fabsf(esh[t]) : 0.0f);
    lo_ = dsh[t] - r;
    hi_ = dsh[t] + r;
  }
#pragma unroll
  for (int off = 1; off < 64; off <<= 1) {
    lo_ = fminf(lo_, __shfl_xor(lo_, off, 64));
    hi_ = fmaxf(hi_, __shfl_xor(hi_, off, 64));
  }
  if (lane == 0) { red[wv] = lo_; red2[wv] = hi_; }
  __syncthreads();                          // also fences e2sh/dsh
  lo_ = red[0]; hi_ = red2[0];
#pragma unroll
  for (int u = 1; u < 10; ++u) { lo_ = fminf(lo_, red[u]); hi_ = fmaxf(hi_, red2[u]); }
  const float span = hi_ - lo_;
  const float glo = lo_ - 0.001f * span - 1e-6f;
  const float ghi = hi_ + 0.001f * span + 1e-6f;

  // 9-section search via Sturm count: 8 probe lanes per eigenvalue, 13 rounds
  {
    const int e = t >> 3;        // eigenvalue index 0..79 (77..79 inactive)
    const int s = t & 7;         // probe lane within oct
    const int g = (t & 63) >> 3; // oct group within wave
    float lo = glo, hi = ghi;
    for (int r = 0; r < 13; ++r) {
      const float step = (hi - lo) * (1.0f / 9.0f);
      const float x = fmaf(step, (float)(s + 1), lo);
      float q = dsh[0] - x;
      int cnt = (q < 0.0f);
#pragma unroll 4
      for (int i = 1; i < 77; ++i) {
        q = (fabsf(q) < 1e-30f) ? -1e-30f : q;
        q = dsh[i] - x - e2sh[i - 1] * __builtin_amdgcn_rcpf(q);
        cnt += (q < 0.0f);
      }
      const unsigned long long mask = __ballot(cnt > e);
      const int b = (int)((mask >> (g * 8)) & 0xFFull);
      const int z = b ? __builtin_ctz(b) : 8;   // probes with cnt<=e
      const float nlo = fmaf(step, (float)z, lo);
      hi = (z == 8) ? hi : fmaf(step, (float)(z + 1), lo);
      lo = nlo;
    }
    if (s == 0 && e < 77) eout[76 - e] = 0.5f * (lo + hi);  // descending
  }
}

// ---------------- launch ----------------
extern "C" void kernel_launch(void* const* d_in, const int* in_sizes, int n_in,
                              void* d_out, int out_size, void* d_ws, size_t ws_size,
                              hipStream_t stream) {
  const float* omega  = (const float*)d_in[0];
  const float* Phi    = (const float*)d_in[1];
  const float* metric = (const float*)d_in[2];
  for (int q = 0; q < n_in && q < 3; ++q) {
    if (in_sizes[q] == SZ_OMEGA)       omega  = (const float*)d_in[q];
    else if (in_sizes[q] == SZ_PHI)    Phi    = (const float*)d_in[q];
    else if (in_sizes[q] == SZ_METRIC) metric = (const float*)d_in[q];
  }

  float* out = (float*)d_out;
  float* ws  = (float*)d_ws;   // needs (WS2OFF + 160)*4 ~ 1.14 MB

  // out[0 .. Y_SIZE)           : finalized Y
  // out[VOLOFF .. VOLOFF+4096) : vol[n] (temp, overwritten by gram's M)
  // out[VSUM]                  : volsum (temp, overwritten by gram's M)
  // ws[0 .. WS2OFF)            : NSLOT partial-S slots
  // ws[WS2OFF .. +160)         : tridiagonal d/e scratch
  hipMemsetAsync(d_out, 0, (size_t)out_size * sizeof(float), stream);
  hipMemsetAsync(d_ws, 0, (size_t)WS2OFF * sizeof(float), stream);

  hipLaunchKernelGGL(vol_kernel, dim3(NBATCH / 256), dim3(256), 0, stream, metric, out);
  hipLaunchKernelGGL(contract_kernel, dim3(GRID_B), dim3(BLK), 0, stream,
                     omega, Phi, out, ws);
  hipLaunchKernelGGL(finalize_y, dim3((NPAIR * NK + 255) / 256), dim3(256), 0, stream,
                     ws, out);
  hipLaunchKernelGGL(gram_kernel, dim3(NK), dim3(EIGT), 0, stream,
                     out, out + Y_SIZE);
  hipLaunchKernelGGL(tridiag_kernel, dim3(1), dim3(64), 0, stream,
                     out + Y_SIZE, ws + WS2OFF);
  hipLaunchKernelGGL(bisect_kernel, dim3(1), dim3(EIGT), 0, stream,
                     ws + WS2OFF, out + Y_SIZE + M_SIZE);
}

// Round 10
// 316.495 us; speedup vs baseline: 1.7627x; 1.0877x over previous
//
#include <hip/hip_runtime.h>
#include <math.h>

#define NBATCH 4096
#define NH2 21
#define NK 77
#define NC 35
#define NIJ 441
#define Y_SIZE 33957
#define M_SIZE 5929
#define VOLOFF Y_SIZE          // vol[n] at out[VOLOFF + n] (temp, inside M region)
#define VSUM (Y_SIZE + 4096)   // volsum at out[VSUM] (temp, inside M region)
#define NPAIR 231              // upper-triangular (i<=j) pairs of 21
#define BLK 512                // contract block threads (8 waves)
#define NPB 16                 // R20: n per contract block 8->16: atomic count
                               // 9.1M->4.55M (atomic-drain ~80us -> ~40us),
                               // 256 blocks = 1/CU, slots 16 blocks/slot.
#define GRID_B (NBATCH / NPB)  // 256 blocks
#define EIGT 640               // bisect block: 10 waves (verified 9-section code)
#define LDS_K 72               // R19: D/P row stride in shorts (2-way = free)

// workspace layout (d_ws): NSLOT partial-S slots + tridiag d/e scratch
#define NSLOT 16
#define SLOT_STRIDE 17792      // NPAIR*NK=17787 padded
#define WS2OFF (NSLOT * SLOT_STRIDE)   // 284672 floats; ws total ~1.14 MB

#define SZ_OMEGA  (NBATCH * NH2 * NH2)   // 1,806,336
#define SZ_PHI    (NBATCH * NK * NC)     // 11,038,720
#define SZ_METRIC (NBATCH * 7 * 7)      // 200,704

// ---------------- compile-time wedge structure constants ----------------
// C[a,b,c] nonzero iff pair_a, pair_b, triple_c partition {0..6}; value = perm
// sign. Exactly 6 (a,b) terms per c. MUST be a constexpr LOCAL in each kernel
// (round-3 finding). C[a,b,c]=C[b,a,c] => S symmetric in (i,j): only i<=j pairs.
// R5: never cap VGPRs below live set (spill -> 5x).
// R12: shfl == ds_bpermute ~120-150cy LDS hop; DPP adds ~5cy.
// R13: single-WAVE tridiag (A in VGPRs, zero barriers).
// R16: tridiag schedule PINNED (R15/R17/R18 restructures all failed).
// R17 FAILED: fusing tridiag into 640-thr block -> VGPR cap 84 -> spill (R5).
// R18/R19 LESSON: rocprof per-dispatch times for the 1-wave tridiag are
//   clock-state artifacts across sessions (107 vs 206us for bit-identical
//   code; totals flat). TRUST dur_us ONLY for cross-round deltas.
// Budget (from dur_us): total 344 = tridiag ~108 (pinned) + contract-chain
//   ~235 (flat since R13). Contract's 9.1M fp32 atomics ~ 80us of L2 atomic
//   drain (count-bound, not contention-bound) -> R20 halves the count.
// R7: LDS strides sharing a factor with the bank-group period -> conflicts.
// R8: 2-barrier staged VALU loop plateaus ~27% VALUBusy -> moved to MFMA (R9).
struct WTab {
  int a[NC][6];
  int b[NC][6];
  int sg[NC][6];
};

constexpr WTab make_wtab() {
  WTab W{};
  int p0[21] = {}, p1[21] = {};
  int idx = 0;
  for (int x = 0; x < 7; ++x)
    for (int y = x + 1; y < 7; ++y) { p0[idx] = x; p1[idx] = y; ++idx; }
  int t0[35] = {}, t1[35] = {}, t2[35] = {};
  idx = 0;
  for (int x = 0; x < 7; ++x)
    for (int y = x + 1; y < 7; ++y)
      for (int z = y + 1; z < 7; ++z) { t0[idx] = x; t1[idx] = y; t2[idx] = z; ++idx; }
  int cnt[35] = {};
  for (int a = 0; a < 21; ++a)
    for (int b = 0; b < 21; ++b) {
      int pa0 = p0[a], pa1 = p1[a], pb0 = p0[b], pb1 = p1[b];
      if (pa0 == pb0 || pa0 == pb1 || pa1 == pb0 || pa1 == pb1) continue;
      bool used[7] = {};
      used[pa0] = true; used[pa1] = true; used[pb0] = true; used[pb1] = true;
      int tr[3] = {}; int k = 0;
      for (int x = 0; x < 7; ++x) if (!used[x]) tr[k++] = x;
      int c = -1;
      for (int cc = 0; cc < 35; ++cc)
        if (t0[cc] == tr[0] && t1[cc] == tr[1] && t2[cc] == tr[2]) { c = cc; break; }
      int perm[7] = {pa0, pa1, pb0, pb1, tr[0], tr[1], tr[2]};
      int inv = 0;
      for (int i = 0; i < 7; ++i)
        for (int j = i + 1; j < 7; ++j)
          if (perm[i] > perm[j]) ++inv;
      W.a[c][cnt[c]] = a; W.b[c][cnt[c]] = b; W.sg[c][cnt[c]] = (inv & 1) ? -1 : 1;
      ++cnt[c];
    }
  return W;
}

__device__ __forceinline__ int trioff(int i) { return 21 * i - (i * (i - 1)) / 2; }

// fp32 -> bf16 (RNE), returns low 16 bits
__device__ __forceinline__ unsigned f2bf(float x) {
  union { float f; unsigned u; } v; v.f = x;
  return ((v.u + 0x7FFFu + ((v.u >> 16) & 1u)) >> 16) & 0xFFFFu;
}

typedef float f32x4 __attribute__((ext_vector_type(4)));
typedef float f32x2 __attribute__((ext_vector_type(2)));
typedef short s16x8 __attribute__((ext_vector_type(8)));

// packed fp32 FMA (VOP3P, gfx90a+): d = a*b + c per 32-bit half. NOT volatile.
__device__ __forceinline__ f32x2 pk_fma(f32x2 a, f32x2 b, f32x2 c) {
  f32x2 d;
  asm("v_pk_fma_f32 %0, %1, %2, %3" : "=v"(d) : "v"(a), "v"(b), "v"(c));
  return d;
}

// ---------------- DPP wave reductions (R12): VALU-latency, no LDS pipe -------
template <int CTRL>
__device__ __forceinline__ float dppadd(float x) {
  union { float f; int i; } u, r;
  u.f = x;
  r.i = __builtin_amdgcn_update_dpp(0, u.i, CTRL, 0xF, 0xF, true);
  return x + r.f;
}
// sum over each aligned group of 8 lanes; result in ALL 8 lanes of the group
__device__ __forceinline__ float oct_sum(float x) {
  x = dppadd<0xB1>(x);    // quad_perm(1,0,3,2)  : + xor1
  x = dppadd<0x4E>(x);    // quad_perm(2,3,0,1)  : + xor2
  x = dppadd<0x141>(x);   // row_half_mirror     : + other quad of 8
  return x;
}
// sum over all 64 lanes; result valid in lane 63
__device__ __forceinline__ float wave_sum(float x) {
  x = dppadd<0xB1>(x);
  x = dppadd<0x4E>(x);
  x = dppadd<0x141>(x);
  x = dppadd<0x140>(x);   // row_mirror
  x = dppadd<0x142>(x);   // row_bcast15
  x = dppadd<0x143>(x);   // row_bcast31
  return x;
}
__device__ __forceinline__ float readlane63(float x) {
  union { float f; int i; } u; u.f = x;
  union { int i; float f; } r;
  r.i = __builtin_amdgcn_readlane(u.i, 63);
  return r.f;
}
__device__ __forceinline__ float readlane0(float x) {
  union { float f; int i; } u; u.f = x;
  union { int i; float f; } r;
  r.i = __builtin_amdgcn_readfirstlane(u.i);
  return r.f;
}
__device__ __forceinline__ float readlaneN(float x, int lane) {
  union { float f; int i; } u; u.f = x;
  union { int i; float f; } r;
  r.i = __builtin_amdgcn_readlane(u.i, lane);
  return r.f;
}

// ---------------- kernel A: vol[n] = sqrt(|det(metric_n)|), + sum ----------------
__global__ __launch_bounds__(256) void vol_kernel(const float* __restrict__ metric,
                                                  float* __restrict__ out) {
  const int n = blockIdx.x * 256 + threadIdx.x;
  double a[7][7];
#pragma unroll
  for (int r = 0; r < 7; ++r)
#pragma unroll
    for (int c = 0; c < 7; ++c) a[r][c] = (double)metric[n * 49 + r * 7 + c];

  double det = 1.0;
#pragma unroll
  for (int k = 0; k < 7; ++k) {
#pragma unroll
    for (int r = k + 1; r < 7; ++r) {
      bool sw = fabs(a[r][k]) > fabs(a[k][k]);
#pragma unroll
      for (int c = k; c < 7; ++c) {
        double u = a[k][c], v = a[r][c];
        a[k][c] = sw ? v : u;
        a[r][c] = sw ? u : v;
      }
    }
    det *= a[k][k];
    double inv = (a[k][k] != 0.0) ? 1.0 / a[k][k] : 0.0;
#pragma unroll
    for (int r = k + 1; r < 7; ++r) {
      double f = a[r][k] * inv;
#pragma unroll
      for (int c = k + 1; c < 7; ++c) a[r][c] -= f * a[k][c];
    }
  }
  float vol = (float)sqrt(fabs(det));
  out[VOLOFF + n] = vol;

  float s = vol;
#pragma unroll
  for (int off = 32; off > 0; off >>= 1) s += __shfl_down(s, off, 64);
  __shared__ float partial[4];
  const int lane = threadIdx.x & 63, wv = threadIdx.x >> 6;
  if (lane == 0) partial[wv] = s;
  __syncthreads();
  if (threadIdx.x == 0)
    atomicAdd(out + VSUM, partial[0] + partial[1] + partial[2] + partial[3]);
}

// ---------------- kernel B: MFMA contract (R20: NPB=16, stride-72 LDS) --------
__global__ __launch_bounds__(BLK) void contract_kernel(const float* __restrict__ omega,
                                                       const float* __restrict__ Phi,
                                                       const float* __restrict__ out,
                                                       float* __restrict__ wsS) {
  constexpr WTab W = make_wtab();
  __shared__ __align__(16) short ldsD[256 * LDS_K];  // D rows, stride 72 bf16
  __shared__ __align__(16) short ldsP[80 * LDS_K];   // PW^T rows [q][k]
  __shared__ __align__(16) float ldsO[NH2 * 28];     // omega rows, stride 28 fp32

  const int t = threadIdx.x;
  const int lane = t & 63;
  const int wv = t >> 6;
  const int quad = lane >> 4;
  const int col = lane & 15;
  const int n0 = blockIdx.x * NPB;

  for (int f = t; f < 256 * (LDS_K / 2); f += BLK) ((int*)ldsD)[f] = 0;
  for (int f = t; f < 80 * (LDS_K / 2); f += BLK) ((int*)ldsP)[f] = 0;

  const bool roleA = (t < NPAIR);
  const bool roleB = (t >= 256) && (t < 256 + NPAIR);
  int pi = 0, pj = 0;
  {
    const int p = roleA ? t : (roleB ? (t - 256) : 0);
    int i = 0;
    while (i < 20 && trioff(i + 1) <= p) ++i;
    pi = i;
    pj = p - trioff(i) + i;
  }

  float rA = 0.0f, rB[6], rvn;
  {
    const float* om = omega + n0 * 441;
    const float* ph = Phi + n0 * 2695;
    if (t < 441) rA = om[t];
#pragma unroll
    for (int j = 0; j < 6; ++j) {
      const int e = t + j * BLK;
      rB[j] = (e < 2695) ? ph[e] : 0.0f;
    }
    rvn = out[VOLOFF + n0];
  }

  f32x4 acc[2][5];
#pragma unroll
  for (int mi = 0; mi < 2; ++mi)
#pragma unroll
    for (int nt = 0; nt < 5; ++nt) acc[mi][nt] = (f32x4){0.f, 0.f, 0.f, 0.f};

  for (int it = 0; it < NPB; ++it) {
    __syncthreads();

    if (t < 441) ldsO[(t / 21) * 28 + (t % 21)] = rA;
    {
      const float vn = rvn;
#pragma unroll
      for (int j = 0; j < 6; ++j) {
        const int e = t + j * BLK;
        if (e < 2695) {
          const int q = e / 35, c = e % 35;
          ldsP[q * LDS_K + c] = (short)f2bf(vn * rB[j]);
        }
      }
    }
    __syncthreads();

    if (it + 1 < NPB) {
      const int n1 = n0 + it + 1;
      const float* om2 = omega + n1 * 441;
      const float* ph2 = Phi + n1 * 2695;
      if (t < 441) rA = om2[t];
#pragma unroll
      for (int j = 0; j < 6; ++j) {
        const int e = t + j * BLK;
        if (e < 2695) rB[j] = ph2[e];
      }
      rvn = out[VOLOFF + n1];
    }

    if (roleA || roleB) {
      float wi[21], wj[21];
      const float* oi = ldsO + pi * 28;
      const float* oj = ldsO + pj * 28;
#pragma unroll
      for (int a = 0; a < 20; a += 4) {
        float4 v = *(const float4*)(oi + a);
        wi[a] = v.x; wi[a + 1] = v.y; wi[a + 2] = v.z; wi[a + 3] = v.w;
        float4 u = *(const float4*)(oj + a);
        wj[a] = u.x; wj[a + 1] = u.y; wj[a + 2] = u.z; wj[a + 3] = u.w;
      }
      wi[20] = oi[20]; wj[20] = oj[20];

      if (roleA) {
        float d[18];
#pragma unroll
        for (int c = 0; c < 18; ++c) {
          float dd = 0.0f;
#pragma unroll
          for (int u = 0; u < 6; ++u)
            dd = fmaf((W.sg[c][u] > 0) ? wi[W.a[c][u]] : -wi[W.a[c][u]], wj[W.b[c][u]], dd);
          d[c] = dd;
        }
        int* Drow = (int*)ldsD + t * (LDS_K / 2);
#pragma unroll
        for (int k2 = 0; k2 < 9; ++k2)
          Drow[k2] = (int)(f2bf(d[2 * k2]) | (f2bf(d[2 * k2 + 1]) << 16));
      } else {
        float d[17];
#pragma unroll
        for (int c = 18; c < 35; ++c) {
          float dd = 0.0f;
#pragma unroll
          for (int u = 0; u < 6; ++u)
            dd = fmaf((W.sg[c][u] > 0) ? wi[W.a[c][u]] : -wi[W.a[c][u]], wj[W.b[c][u]], dd);
          d[c - 18] = dd;
        }
        int* Drow = (int*)ldsD + (t - 256) * (LDS_K / 2);
#pragma unroll
        for (int k2 = 0; k2 < 8; ++k2)
          Drow[9 + k2] = (int)(f2bf(d[2 * k2]) | (f2bf(d[2 * k2 + 1]) << 16));
        Drow[17] = (int)f2bf(d[16]);
      }
    }
    __syncthreads();

#pragma unroll
    for (int s = 0; s < 2; ++s) {
      const int kof = s * 32 + quad * 8;
      s16x8 a0 = *(const s16x8*)(ldsD + ((wv * 2 + 0) * 16 + col) * LDS_K + kof);
      s16x8 a1 = *(const s16x8*)(ldsD + ((wv * 2 + 1) * 16 + col) * LDS_K + kof);
      s16x8 b[5];
#pragma unroll
      for (int nt = 0; nt < 5; ++nt)
        b[nt] = *(const s16x8*)(ldsP + (nt * 16 + col) * LDS_K + kof);
#pragma unroll
      for (int nt = 0; nt < 5; ++nt) {
        acc[0][nt] = __builtin_amdgcn_mfma_f32_16x16x32_bf16(a0, b[nt], acc[0][nt], 0, 0, 0);
        acc[1][nt] = __builtin_amdgcn_mfma_f32_16x16x32_bf16(a1, b[nt], acc[1][nt], 0, 0, 0);
      }
    }
  }

  // scatter into one of NSLOT partial copies (16 blocks/slot at GRID_B=256)
  float* slot = wsS + (size_t)(blockIdx.x & (NSLOT - 1)) * SLOT_STRIDE;
#pragma unroll
  for (int mi = 0; mi < 2; ++mi) {
    const int mt = wv * 2 + mi;
#pragma unroll
    for (int r = 0; r < 4; ++r) {
      const int m = mt * 16 + quad * 4 + r;
      if (m < NPAIR) {
#pragma unroll
        for (int nt = 0; nt < 5; ++nt) {
          const int q = nt * 16 + col;
          if (q < 77) atomicAdd(&slot[m * NK + q], acc[mi][nt][r]);
        }
      }
    }
  }
}

// ---------------- kernel C1: finalize Y from slot partials ----------------
__global__ __launch_bounds__(256) void finalize_y(const float* __restrict__ wsS,
                                                  float* __restrict__ out) {
  const int e = blockIdx.x * 256 + threadIdx.x;
  if (e >= NPAIR * NK) return;
  const int p = e / NK, k = e % NK;
  int i = 0;
  while (i < 20 && trioff(i + 1) <= p) ++i;
  const int j = p - trioff(i) + i;
  float v = 0.0f;
#pragma unroll
  for (int s = 0; s < NSLOT; ++s) v += wsS[(size_t)s * SLOT_STRIDE + p * NK + k];
  v *= 1.0f / out[VSUM];
  out[(i * 21 + j) * NK + k] = v;
  if (j != i) out[(j * 21 + i) * NK + k] = -v;
}

// ---------------- kernel C2: M[k,l] = sum_ij Y_ij,k Y_ij,l (R14) ----------------
__global__ __launch_bounds__(EIGT) void gram_kernel(const float* __restrict__ Y,
                                                    float* __restrict__ Mout) {
  const int k = blockIdx.x;
  const int t = threadIdx.x;
  const int l = t >> 3, s = t & 7;
  float acc = 0.0f;
  if (l < NK) {
    for (int ij = s; ij < NIJ; ij += 8)
      acc = fmaf(Y[ij * NK + k], Y[ij * NK + l], acc);
  }
  acc = oct_sum(acc);
  if (s == 0 && l < NK) Mout[k * NK + l] = acc;
}

// ---------------- kernel D1: single-wave Householder tridiag (R16, PINNED) ----
// One wave, A[80x80] in VGPRs as f32x2 col-pairs: lane l=(br<<3)|bc owns rows
// [10br,+10) x col-pairs [5bc,+5). Zero barriers, zero LDS.
// R15/R17/R18 restructures all regressed — do not modify the schedule.
__global__ __launch_bounds__(64, 1) void tridiag_kernel(const float* __restrict__ Min,
                                                        float* __restrict__ ws2) {
  const int l = threadIdx.x;
  const int br = l >> 3, bc = l & 7;
  f32x2 A2[10][5];
#pragma unroll
  for (int r = 0; r < 10; ++r) {
    const int g = 10 * br + r;
#pragma unroll
    for (int c2 = 0; c2 < 5; ++c2) {
      const int gc0 = 10 * bc + 2 * c2;
      A2[r][c2][0] = (g < 77 && gc0 < 77) ? Min[g * 77 + gc0] : 0.0f;
      A2[r][c2][1] = (g < 77 && gc0 + 1 < 77) ? Min[g * 77 + gc0 + 1] : 0.0f;
    }
  }

  // prologue: broadcast row 0 (col-chunks from lane bc, row-chunks from lane br)
  float rc[10], rr[10];
#pragma unroll
  for (int c2 = 0; c2 < 5; ++c2) {
    rc[2 * c2]     = __shfl(A2[0][c2][0], bc, 64);
    rc[2 * c2 + 1] = __shfl(A2[0][c2][1], bc, 64);
    rr[2 * c2]     = __shfl(A2[0][c2][0], br, 64);
    rr[2 * c2 + 1] = __shfl(A2[0][c2][1], br, 64);
  }

#pragma unroll 1
  for (int kb = 0; kb < 8; ++kb) {
#pragma unroll
    for (int ko = 0; ko < 10; ++ko) {
      if (kb == 7 && ko >= 5) break;           // k stops at 74
      const int k = kb * 10 + ko;
      const int nko = (ko + 1) % 10;           // literal after unroll
      const int nkb = kb + (ko == 9 ? 1 : 0);
      const int nic = nkb * 8 + bc, nir = nkb * 8 + br;

      // sigma2 partials (br==0 lanes = oct 0) -> 3-hop oct_sum + readfirstlane
      float part = 0.0f;
      if (br == 0) {
#pragma unroll
        for (int c2 = 0; c2 < 5; ++c2) {
          const int gc0 = 10 * bc + 2 * c2;
          const float x0 = rc[2 * c2], xv = rc[2 * c2 + 1];
          part += (gc0 > k) ? x0 * x0 : 0.0f;
          part += (gc0 + 1 > k) ? xv * xv : 0.0f;
        }
      }
      part = oct_sum(part);
      const float sigma2 = readlane0(part);
      if (sigma2 < 1e-26f) {                   // uniform branch, rare
        if (l == 0) ws2[80 + k] = 0.0f;
#pragma unroll
        for (int c2 = 0; c2 < 5; ++c2) {       // still pipeline next bcast
          rc[2 * c2]     = __shfl(A2[nko][c2][0], nic, 64);
          rc[2 * c2 + 1] = __shfl(A2[nko][c2][1], nic, 64);
          rr[2 * c2]     = __shfl(A2[nko][c2][0], nir, 64);
          rr[2 * c2 + 1] = __shfl(A2[nko][c2][1], nir, 64);
        }
        continue;
      }
      // x1 = A[k][k+1]: col k+1 sits in rc[nko] of lanes with bc==nkb
      const float x1 = readlaneN(rc[nko], nkb);
      const float sigma = __builtin_amdgcn_sqrtf(sigma2);
      const float alpha = (x1 >= 0.0f) ? -sigma : sigma;
      const float beta = __builtin_amdgcn_rcpf(fmaf(-alpha, x1, sigma2));
      const float xha = x1 - alpha;
      if (l == 0) ws2[80 + k] = alpha;

      // v over own cols (from rc) and own rows (from rr) — both local
      f32x2 vc2[5];
      float vr[10];
#pragma unroll
      for (int c2 = 0; c2 < 5; ++c2) {
        const int gc0 = 10 * bc + 2 * c2;
        vc2[c2][0] = (gc0 > k) ? ((gc0 == k + 1) ? xha : rc[2 * c2]) : 0.0f;
        vc2[c2][1] = (gc0 + 1 > k) ? ((gc0 + 1 == k + 1) ? xha : rc[2 * c2 + 1]) : 0.0f;
        const int gr0 = 10 * br + 2 * c2;
        vr[2 * c2] = (gr0 > k) ? ((gr0 == k + 1) ? xha : rr[2 * c2]) : 0.0f;
        vr[2 * c2 + 1] = (gr0 + 1 > k) ? ((gr0 + 1 == k + 1) ? xha : rr[2 * c2 + 1]) : 0.0f;
      }

      // p = beta * A v (packed fma; rows independent)
      float p[10];
#pragma unroll
      for (int r = 0; r < 10; ++r) {
        f32x2 a = (f32x2){0.f, 0.f};
#pragma unroll
        for (int c2 = 0; c2 < 5; ++c2) a = pk_fma(A2[r][c2], vc2[c2], a);
        p[r] = a[0] + a[1];
      }
#pragma unroll
      for (int r = 0; r < 10; ++r) {
        p[r] = oct_sum(p[r]) * beta;
        p[r] = (10 * br + r > k) ? p[r] : 0.0f;
      }

      // prefetch p-by-columns NOW (hides under the K reduction)
      f32x2 pc2[5];
#pragma unroll
      for (int c2 = 0; c2 < 5; ++c2) {
        pc2[c2][0] = __shfl(p[2 * c2], 9 * bc, 64);
        pc2[c2][1] = __shfl(p[2 * c2 + 1], 9 * bc, 64);
      }

      // K = p . v (rows counted once: bc==0 lanes)
      float kp = 0.0f;
      if (bc == 0) {
#pragma unroll
        for (int r = 0; r < 10; ++r) kp = fmaf(p[r], vr[r], kp);
      }
      kp = wave_sum(kp);
      const float hb = 0.5f * beta * readlane63(kp);

      // w by rows (local); wc by cols LOCAL from prefetched pc
      float w[10];
#pragma unroll
      for (int r = 0; r < 10; ++r) w[r] = fmaf(-hb, vr[r], p[r]);
      const f32x2 mhb = (f32x2){-hb, -hb};
      f32x2 wc2[5];
#pragma unroll
      for (int c2 = 0; c2 < 5; ++c2) wc2[c2] = pk_fma(mhb, vc2[c2], pc2[c2]);

      // rank-2 update: pivot row nko FIRST, issue next broadcast, then rest
      {
        const f32x2 nv = (f32x2){-vr[nko], -vr[nko]};
        const f32x2 nw = (f32x2){-w[nko], -w[nko]};
#pragma unroll
        for (int c2 = 0; c2 < 5; ++c2)
          A2[nko][c2] = pk_fma(nv, wc2[c2], pk_fma(nw, vc2[c2], A2[nko][c2]));
      }
#pragma unroll
      for (int c2 = 0; c2 < 5; ++c2) {
        rc[2 * c2]     = __shfl(A2[nko][c2][0], nic, 64);
        rc[2 * c2 + 1] = __shfl(A2[nko][c2][1], nic, 64);
        rr[2 * c2]     = __shfl(A2[nko][c2][0], nir, 64);
        rr[2 * c2 + 1] = __shfl(A2[nko][c2][1], nir, 64);
      }
#pragma unroll
      for (int r = 0; r < 10; ++r) {
        if (r == nko) continue;
        const f32x2 nv = (f32x2){-vr[r], -vr[r]};
        const f32x2 nw = (f32x2){-w[r], -w[r]};
#pragma unroll
        for (int c2 = 0; c2 < 5; ++c2)
          A2[r][c2] = pk_fma(nv, wc2[c2], pk_fma(nw, vc2[c2], A2[r][c2]));
      }
    }
  }

  // gather tridiagonal: diag from lanes br==bc, last offdiag from lane 63
  if (br == bc) {
#pragma unroll
    for (int e = 0; e < 10; ++e)
      ws2[10 * br + e] = (e & 1) ? A2[e][e / 2][1] : A2[e][e / 2][0];
  }
  if (l == 63) ws2[80 + 75] = A2[6][2][1];     // A[76][75]
}

// ---------------- kernel D2: bisection (verified 9-section, 640 thr) ----------
__global__ __launch_bounds__(EIGT) void bisect_kernel(const float* __restrict__ ws2,
                                                      float* __restrict__ eout) {
  __shared__ float dsh[80], esh[80], e2sh[80];
  __shared__ float red[10], red2[10];
  const int t = threadIdx.x;
  const int lane = t & 63, wv = t >> 6;
  if (t < 80) {
    dsh[t] = ws2[t];
    esh[t] = (t < 76) ? ws2[80 + t] : 0.0f;
  }
  __syncthreads();
  if (t < 76) e2sh[t] = esh[t] * esh[t];

  // Gershgorin bounds (parallel reduce)
  float lo_ = 1e30f, hi_ = -1e30f;
  if (t < 77) {
    const float r = ((t > 0) ? fabsf(esh[t - 1]) : 0.0f) +
                    ((t < 76) ? fabsf(esh[t]) : 0.0f);
    lo_ = dsh[t] - r;
    hi_ = dsh[t] + r;
  }
#pragma unroll
  for (int off = 1; off < 64; off <<= 1) {
    lo_ = fminf(lo_, __shfl_xor(lo_, off, 64));
    hi_ = fmaxf(hi_, __shfl_xor(hi_, off, 64));
  }
  if (lane == 0) { red[wv] = lo_; red2[wv] = hi_; }
  __syncthreads();                          // also fences e2sh/dsh
  lo_ = red[0]; hi_ = red2[0];
#pragma unroll
  for (int u = 1; u < 10; ++u) { lo_ = fminf(lo_, red[u]); hi_ = fmaxf(hi_, red2[u]); }
  const float span = hi_ - lo_;
  const float glo = lo_ - 0.001f * span - 1e-6f;
  const float ghi = hi_ + 0.001f * span + 1e-6f;

  // 9-section search via Sturm count: 8 probe lanes per eigenvalue, 13 rounds
  {
    const int e = t >> 3;        // eigenvalue index 0..79 (77..79 inactive)
    const int s = t & 7;         // probe lane within oct
    const int g = (t & 63) >> 3; // oct group within wave
    float lo = glo, hi = ghi;
    for (int r = 0; r < 13; ++r) {
      const float step = (hi - lo) * (1.0f / 9.0f);
      const float x = fmaf(step, (float)(s + 1), lo);
      float q = dsh[0] - x;
      int cnt = (q < 0.0f);
#pragma unroll 4
      for (int i = 1; i < 77; ++i) {
        q = (fabsf(q) < 1e-30f) ? -1e-30f : q;
        q = dsh[i] - x - e2sh[i - 1] * __builtin_amdgcn_rcpf(q);
        cnt += (q < 0.0f);
      }
      const unsigned long long mask = __ballot(cnt > e);
      const int b = (int)((mask >> (g * 8)) & 0xFFull);
      const int z = b ? __builtin_ctz(b) : 8;   // probes with cnt<=e
      const float nlo = fmaf(step, (float)z, lo);
      hi = (z == 8) ? hi : fmaf(step, (float)(z + 1), lo);
      lo = nlo;
    }
    if (s == 0 && e < 77) eout[76 - e] = 0.5f * (lo + hi);  // descending
  }
}

// ---------------- launch ----------------
extern "C" void kernel_launch(void* const* d_in, const int* in_sizes, int n_in,
                              void* d_out, int out_size, void* d_ws, size_t ws_size,
                              hipStream_t stream) {
  const float* omega  = (const float*)d_in[0];
  const float* Phi    = (const float*)d_in[1];
  const float* metric = (const float*)d_in[2];
  for (int q = 0; q < n_in && q < 3; ++q) {
    if (in_sizes[q] == SZ_OMEGA)       omega  = (const float*)d_in[q];
    else if (in_sizes[q] == SZ_PHI)    Phi    = (const float*)d_in[q];
    else if (in_sizes[q] == SZ_METRIC) metric = (const float*)d_in[q];
  }

  float* out = (float*)d_out;
  float* ws  = (float*)d_ws;   // needs (WS2OFF + 160)*4 ~ 1.14 MB

  // out[0 .. Y_SIZE)           : finalized Y
  // out[VOLOFF .. VOLOFF+4096) : vol[n] (temp, overwritten by gram's M)
  // out[VSUM]                  : volsum (temp, overwritten by gram's M)
  // ws[0 .. WS2OFF)            : NSLOT partial-S slots
  // ws[WS2OFF .. +160)         : tridiagonal d/e scratch
  hipMemsetAsync(d_out, 0, (size_t)out_size * sizeof(float), stream);
  hipMemsetAsync(d_ws, 0, (size_t)WS2OFF * sizeof(float), stream);

  hipLaunchKernelGGL(vol_kernel, dim3(NBATCH / 256), dim3(256), 0, stream, metric, out);
  hipLaunchKernelGGL(contract_kernel, dim3(GRID_B), dim3(BLK), 0, stream,
                     omega, Phi, out, ws);
  hipLaunchKernelGGL(finalize_y, dim3((NPAIR * NK + 255) / 256), dim3(256), 0, stream,
                     ws, out);
  hipLaunchKernelGGL(gram_kernel, dim3(NK), dim3(EIGT), 0, stream,
                     out, out + Y_SIZE);
  hipLaunchKernelGGL(tridiag_kernel, dim3(1), dim3(64), 0, stream,
                     out + Y_SIZE, ws + WS2OFF);
  hipLaunchKernelGGL(bisect_kernel, dim3(1), dim3(EIGT), 0, stream,
                     ws + WS2OFF, out + Y_SIZE + M_SIZE);
}

// Round 11
// 309.696 us; speedup vs baseline: 1.8014x; 1.0220x over previous
//
#include <hip/hip_runtime.h>
#include <math.h>

#define NBATCH 4096
#define NH2 21
#define NK 77
#define NC 35
#define NIJ 441
#define Y_SIZE 33957
#define M_SIZE 5929
#define VOLOFF Y_SIZE          // vol[n] at out[VOLOFF + n] (temp, inside M region)
#define VSUM (Y_SIZE + 4096)   // volsum at out[VSUM] (temp, inside M region)
#define NPAIR 231              // upper-triangular (i<=j) pairs of 21
#define BLK 512                // contract block threads (8 waves)
#define NPB 16                 // R20: 256 blocks = 1/CU
#define GRID_B (NBATCH / NPB)  // 256 blocks
#define EIGT 640               // bisect block: 10 waves (verified 9-section code)
#define LDS_K 72               // R19: D/P row stride in shorts (2-way = free)

// workspace layout (d_ws):
//  R21 privatized (ws_size >= ~18.2MB): GRID_B slots, one per block, PLAIN
//    stores (no atomics, no ws memset — every slot entry written each run).
//  fallback (small ws): NSLOT=16 slots + atomicAdd + memset (R20 path).
#define NSLOT 16
#define SLOT_STRIDE 17792      // NPAIR*NK=17787 padded
#define WS2OFF_FB  (NSLOT * SLOT_STRIDE)    // fallback d/e scratch offset
#define WS2OFF_PRV (GRID_B * SLOT_STRIDE)   // privatized d/e scratch offset
#define WS_NEED_PRV ((size_t)(WS2OFF_PRV + 160) * 4)

#define SZ_OMEGA  (NBATCH * NH2 * NH2)   // 1,806,336
#define SZ_PHI    (NBATCH * NK * NC)     // 11,038,720
#define SZ_METRIC (NBATCH * 7 * 7)       // 200,704

// ---------------- compile-time wedge structure constants ----------------
// C[a,b,c] nonzero iff pair_a, pair_b, triple_c partition {0..6}; value = perm
// sign. Exactly 6 (a,b) terms per c. MUST be a constexpr LOCAL in each kernel
// (round-3 finding). C[a,b,c]=C[b,a,c] => S symmetric in (i,j): only i<=j pairs.
// R5: never cap VGPRs below live set (spill -> 5x).
// R12: shfl == ds_bpermute ~120-150cy LDS hop; DPP adds ~5cy.
// R13: single-WAVE tridiag (A in VGPRs, zero barriers).
// R16: tridiag schedule PINNED (R15/R17/R18 restructures all failed).
// R17 FAILED: fusing tridiag into 640-thr block -> VGPR cap 84 -> spill (R5).
// R18/R19 LESSON: rocprof per-dispatch times for the 1-wave tridiag are
//   clock-state artifacts across sessions. TRUST dur_us ONLY cross-round.
// R20 CONFIRMED (-28us): contract atomic drain is COUNT-bound; NPB 8->16
//   halved 9.1M->4.55M atomics. R21: eliminate them — per-block private
//   slots + plain stores (ws_size-gated, fallback = R20 path).
// R7: LDS strides sharing a factor with the bank-group period -> conflicts.
// R8: 2-barrier staged VALU loop plateaus ~27% VALUBusy -> moved to MFMA (R9).
struct WTab {
  int a[NC][6];
  int b[NC][6];
  int sg[NC][6];
};

constexpr WTab make_wtab() {
  WTab W{};
  int p0[21] = {}, p1[21] = {};
  int idx = 0;
  for (int x = 0; x < 7; ++x)
    for (int y = x + 1; y < 7; ++y) { p0[idx] = x; p1[idx] = y; ++idx; }
  int t0[35] = {}, t1[35] = {}, t2[35] = {};
  idx = 0;
  for (int x = 0; x < 7; ++x)
    for (int y = x + 1; y < 7; ++y)
      for (int z = y + 1; z < 7; ++z) { t0[idx] = x; t1[idx] = y; t2[idx] = z; ++idx; }
  int cnt[35] = {};
  for (int a = 0; a < 21; ++a)
    for (int b = 0; b < 21; ++b) {
      int pa0 = p0[a], pa1 = p1[a], pb0 = p0[b], pb1 = p1[b];
      if (pa0 == pb0 || pa0 == pb1 || pa1 == pb0 || pa1 == pb1) continue;
      bool used[7] = {};
      used[pa0] = true; used[pa1] = true; used[pb0] = true; used[pb1] = true;
      int tr[3] = {}; int k = 0;
      for (int x = 0; x < 7; ++x) if (!used[x]) tr[k++] = x;
      int c = -1;
      for (int cc = 0; cc < 35; ++cc)
        if (t0[cc] == tr[0] && t1[cc] == tr[1] && t2[cc] == tr[2]) { c = cc; break; }
      int perm[7] = {pa0, pa1, pb0, pb1, tr[0], tr[1], tr[2]};
      int inv = 0;
      for (int i = 0; i < 7; ++i)
        for (int j = i + 1; j < 7; ++j)
          if (perm[i] > perm[j]) ++inv;
      W.a[c][cnt[c]] = a; W.b[c][cnt[c]] = b; W.sg[c][cnt[c]] = (inv & 1) ? -1 : 1;
      ++cnt[c];
    }
  return W;
}

__device__ __forceinline__ int trioff(int i) { return 21 * i - (i * (i - 1)) / 2; }

// fp32 -> bf16 (RNE), returns low 16 bits
__device__ __forceinline__ unsigned f2bf(float x) {
  union { float f; unsigned u; } v; v.f = x;
  return ((v.u + 0x7FFFu + ((v.u >> 16) & 1u)) >> 16) & 0xFFFFu;
}

typedef float f32x4 __attribute__((ext_vector_type(4)));
typedef float f32x2 __attribute__((ext_vector_type(2)));
typedef short s16x8 __attribute__((ext_vector_type(8)));

// packed fp32 FMA (VOP3P, gfx90a+): d = a*b + c per 32-bit half. NOT volatile.
__device__ __forceinline__ f32x2 pk_fma(f32x2 a, f32x2 b, f32x2 c) {
  f32x2 d;
  asm("v_pk_fma_f32 %0, %1, %2, %3" : "=v"(d) : "v"(a), "v"(b), "v"(c));
  return d;
}

// ---------------- DPP wave reductions (R12): VALU-latency, no LDS pipe -------
template <int CTRL>
__device__ __forceinline__ float dppadd(float x) {
  union { float f; int i; } u, r;
  u.f = x;
  r.i = __builtin_amdgcn_update_dpp(0, u.i, CTRL, 0xF, 0xF, true);
  return x + r.f;
}
// sum over each aligned group of 8 lanes; result in ALL 8 lanes of the group
__device__ __forceinline__ float oct_sum(float x) {
  x = dppadd<0xB1>(x);    // quad_perm(1,0,3,2)  : + xor1
  x = dppadd<0x4E>(x);    // quad_perm(2,3,0,1)  : + xor2
  x = dppadd<0x141>(x);   // row_half_mirror     : + other quad of 8
  return x;
}
// sum over all 64 lanes; result valid in lane 63
__device__ __forceinline__ float wave_sum(float x) {
  x = dppadd<0xB1>(x);
  x = dppadd<0x4E>(x);
  x = dppadd<0x141>(x);
  x = dppadd<0x140>(x);   // row_mirror
  x = dppadd<0x142>(x);   // row_bcast15
  x = dppadd<0x143>(x);   // row_bcast31
  return x;
}
__device__ __forceinline__ float readlane63(float x) {
  union { float f; int i; } u; u.f = x;
  union { int i; float f; } r;
  r.i = __builtin_amdgcn_readlane(u.i, 63);
  return r.f;
}
__device__ __forceinline__ float readlane0(float x) {
  union { float f; int i; } u; u.f = x;
  union { int i; float f; } r;
  r.i = __builtin_amdgcn_readfirstlane(u.i);
  return r.f;
}
__device__ __forceinline__ float readlaneN(float x, int lane) {
  union { float f; int i; } u; u.f = x;
  union { int i; float f; } r;
  r.i = __builtin_amdgcn_readlane(u.i, lane);
  return r.f;
}

// ---------------- kernel A: vol[n] = sqrt(|det(metric_n)|), + sum ----------------
__global__ __launch_bounds__(256) void vol_kernel(const float* __restrict__ metric,
                                                  float* __restrict__ out) {
  const int n = blockIdx.x * 256 + threadIdx.x;
  double a[7][7];
#pragma unroll
  for (int r = 0; r < 7; ++r)
#pragma unroll
    for (int c = 0; c < 7; ++c) a[r][c] = (double)metric[n * 49 + r * 7 + c];

  double det = 1.0;
#pragma unroll
  for (int k = 0; k < 7; ++k) {
#pragma unroll
    for (int r = k + 1; r < 7; ++r) {
      bool sw = fabs(a[r][k]) > fabs(a[k][k]);
#pragma unroll
      for (int c = k; c < 7; ++c) {
        double u = a[k][c], v = a[r][c];
        a[k][c] = sw ? v : u;
        a[r][c] = sw ? u : v;
      }
    }
    det *= a[k][k];
    double inv = (a[k][k] != 0.0) ? 1.0 / a[k][k] : 0.0;
#pragma unroll
    for (int r = k + 1; r < 7; ++r) {
      double f = a[r][k] * inv;
#pragma unroll
      for (int c = k + 1; c < 7; ++c) a[r][c] -= f * a[k][c];
    }
  }
  float vol = (float)sqrt(fabs(det));
  out[VOLOFF + n] = vol;

  float s = vol;
#pragma unroll
  for (int off = 32; off > 0; off >>= 1) s += __shfl_down(s, off, 64);
  __shared__ float partial[4];
  const int lane = threadIdx.x & 63, wv = threadIdx.x >> 6;
  if (lane == 0) partial[wv] = s;
  __syncthreads();
  if (threadIdx.x == 0)
    atomicAdd(out + VSUM, partial[0] + partial[1] + partial[2] + partial[3]);
}

// ---------------- kernel B: MFMA contract (R21: private-slot stores) ----------
__global__ __launch_bounds__(BLK) void contract_kernel(const float* __restrict__ omega,
                                                       const float* __restrict__ Phi,
                                                       const float* __restrict__ out,
                                                       float* __restrict__ wsS,
                                                       const int priv) {
  constexpr WTab W = make_wtab();
  __shared__ __align__(16) short ldsD[256 * LDS_K];  // D rows, stride 72 bf16
  __shared__ __align__(16) short ldsP[80 * LDS_K];   // PW^T rows [q][k]
  __shared__ __align__(16) float ldsO[NH2 * 28];     // omega rows, stride 28 fp32

  const int t = threadIdx.x;
  const int lane = t & 63;
  const int wv = t >> 6;
  const int quad = lane >> 4;
  const int col = lane & 15;
  const int n0 = blockIdx.x * NPB;

  for (int f = t; f < 256 * (LDS_K / 2); f += BLK) ((int*)ldsD)[f] = 0;
  for (int f = t; f < 80 * (LDS_K / 2); f += BLK) ((int*)ldsP)[f] = 0;

  const bool roleA = (t < NPAIR);
  const bool roleB = (t >= 256) && (t < 256 + NPAIR);
  int pi = 0, pj = 0;
  {
    const int p = roleA ? t : (roleB ? (t - 256) : 0);
    int i = 0;
    while (i < 20 && trioff(i + 1) <= p) ++i;
    pi = i;
    pj = p - trioff(i) + i;
  }

  float rA = 0.0f, rB[6], rvn;
  {
    const float* om = omega + n0 * 441;
    const float* ph = Phi + n0 * 2695;
    if (t < 441) rA = om[t];
#pragma unroll
    for (int j = 0; j < 6; ++j) {
      const int e = t + j * BLK;
      rB[j] = (e < 2695) ? ph[e] : 0.0f;
    }
    rvn = out[VOLOFF + n0];
  }

  f32x4 acc[2][5];
#pragma unroll
  for (int mi = 0; mi < 2; ++mi)
#pragma unroll
    for (int nt = 0; nt < 5; ++nt) acc[mi][nt] = (f32x4){0.f, 0.f, 0.f, 0.f};

  for (int it = 0; it < NPB; ++it) {
    __syncthreads();

    if (t < 441) ldsO[(t / 21) * 28 + (t % 21)] = rA;
    {
      const float vn = rvn;
#pragma unroll
      for (int j = 0; j < 6; ++j) {
        const int e = t + j * BLK;
        if (e < 2695) {
          const int q = e / 35, c = e % 35;
          ldsP[q * LDS_K + c] = (short)f2bf(vn * rB[j]);
        }
      }
    }
    __syncthreads();

    if (it + 1 < NPB) {
      const int n1 = n0 + it + 1;
      const float* om2 = omega + n1 * 441;
      const float* ph2 = Phi + n1 * 2695;
      if (t < 441) rA = om2[t];
#pragma unroll
      for (int j = 0; j < 6; ++j) {
        const int e = t + j * BLK;
        if (e < 2695) rB[j] = ph2[e];
      }
      rvn = out[VOLOFF + n1];
    }

    if (roleA || roleB) {
      float wi[21], wj[21];
      const float* oi = ldsO + pi * 28;
      const float* oj = ldsO + pj * 28;
#pragma unroll
      for (int a = 0; a < 20; a += 4) {
        float4 v = *(const float4*)(oi + a);
        wi[a] = v.x; wi[a + 1] = v.y; wi[a + 2] = v.z; wi[a + 3] = v.w;
        float4 u = *(const float4*)(oj + a);
        wj[a] = u.x; wj[a + 1] = u.y; wj[a + 2] = u.z; wj[a + 3] = u.w;
      }
      wi[20] = oi[20]; wj[20] = oj[20];

      if (roleA) {
        float d[18];
#pragma unroll
        for (int c = 0; c < 18; ++c) {
          float dd = 0.0f;
#pragma unroll
          for (int u = 0; u < 6; ++u)
            dd = fmaf((W.sg[c][u] > 0) ? wi[W.a[c][u]] : -wi[W.a[c][u]], wj[W.b[c][u]], dd);
          d[c] = dd;
        }
        int* Drow = (int*)ldsD + t * (LDS_K / 2);
#pragma unroll
        for (int k2 = 0; k2 < 9; ++k2)
          Drow[k2] = (int)(f2bf(d[2 * k2]) | (f2bf(d[2 * k2 + 1]) << 16));
      } else {
        float d[17];
#pragma unroll
        for (int c = 18; c < 35; ++c) {
          float dd = 0.0f;
#pragma unroll
          for (int u = 0; u < 6; ++u)
            dd = fmaf((W.sg[c][u] > 0) ? wi[W.a[c][u]] : -wi[W.a[c][u]], wj[W.b[c][u]], dd);
          d[c - 18] = dd;
        }
        int* Drow = (int*)ldsD + (t - 256) * (LDS_K / 2);
#pragma unroll
        for (int k2 = 0; k2 < 8; ++k2)
          Drow[9 + k2] = (int)(f2bf(d[2 * k2]) | (f2bf(d[2 * k2 + 1]) << 16));
        Drow[17] = (int)f2bf(d[16]);
      }
    }
    __syncthreads();

#pragma unroll
    for (int s = 0; s < 2; ++s) {
      const int kof = s * 32 + quad * 8;
      s16x8 a0 = *(const s16x8*)(ldsD + ((wv * 2 + 0) * 16 + col) * LDS_K + kof);
      s16x8 a1 = *(const s16x8*)(ldsD + ((wv * 2 + 1) * 16 + col) * LDS_K + kof);
      s16x8 b[5];
#pragma unroll
      for (int nt = 0; nt < 5; ++nt)
        b[nt] = *(const s16x8*)(ldsP + (nt * 16 + col) * LDS_K + kof);
#pragma unroll
      for (int nt = 0; nt < 5; ++nt) {
        acc[0][nt] = __builtin_amdgcn_mfma_f32_16x16x32_bf16(a0, b[nt], acc[0][nt], 0, 0, 0);
        acc[1][nt] = __builtin_amdgcn_mfma_f32_16x16x32_bf16(a1, b[nt], acc[1][nt], 0, 0, 0);
      }
    }
  }

  // R21: private slot -> plain stores (each (m,q) written exactly once per
  // block, so no memset needed); fallback: 16 shared slots + atomics.
  if (priv) {
    float* slot = wsS + (size_t)blockIdx.x * SLOT_STRIDE;
#pragma unroll
    for (int mi = 0; mi < 2; ++mi) {
      const int mt = wv * 2 + mi;
#pragma unroll
      for (int r = 0; r < 4; ++r) {
        const int m = mt * 16 + quad * 4 + r;
        if (m < NPAIR) {
#pragma unroll
          for (int nt = 0; nt < 5; ++nt) {
            const int q = nt * 16 + col;
            if (q < 77) slot[m * NK + q] = acc[mi][nt][r];
          }
        }
      }
    }
  } else {
    float* slot = wsS + (size_t)(blockIdx.x & (NSLOT - 1)) * SLOT_STRIDE;
#pragma unroll
    for (int mi = 0; mi < 2; ++mi) {
      const int mt = wv * 2 + mi;
#pragma unroll
      for (int r = 0; r < 4; ++r) {
        const int m = mt * 16 + quad * 4 + r;
        if (m < NPAIR) {
#pragma unroll
          for (int nt = 0; nt < 5; ++nt) {
            const int q = nt * 16 + col;
            if (q < 77) atomicAdd(&slot[m * NK + q], acc[mi][nt][r]);
          }
        }
      }
    }
  }
}

// ---------------- kernel C1: finalize Y from slot partials ----------------
__global__ __launch_bounds__(256) void finalize_y(const float* __restrict__ wsS,
                                                  float* __restrict__ out,
                                                  const int nslot) {
  const int e = blockIdx.x * 256 + threadIdx.x;
  if (e >= NPAIR * NK) return;
  const int p = e / NK, k = e % NK;
  int i = 0;
  while (i < 20 && trioff(i + 1) <= p) ++i;
  const int j = p - trioff(i) + i;
  float v0 = 0.0f, v1 = 0.0f, v2 = 0.0f, v3 = 0.0f;
  const float* base = wsS + e;
  int s = 0;
#pragma unroll 1
  for (; s + 4 <= nslot; s += 4) {
    v0 += base[(size_t)(s + 0) * SLOT_STRIDE];
    v1 += base[(size_t)(s + 1) * SLOT_STRIDE];
    v2 += base[(size_t)(s + 2) * SLOT_STRIDE];
    v3 += base[(size_t)(s + 3) * SLOT_STRIDE];
  }
  for (; s < nslot; ++s) v0 += base[(size_t)s * SLOT_STRIDE];
  float v = (v0 + v1) + (v2 + v3);
  v *= 1.0f / out[VSUM];
  out[(i * 21 + j) * NK + k] = v;
  if (j != i) out[(j * 21 + i) * NK + k] = -v;
}

// ---------------- kernel C2: M[k,l] = sum_ij Y_ij,k Y_ij,l (R14) ----------------
__global__ __launch_bounds__(EIGT) void gram_kernel(const float* __restrict__ Y,
                                                    float* __restrict__ Mout) {
  const int k = blockIdx.x;
  const int t = threadIdx.x;
  const int l = t >> 3, s = t & 7;
  float acc = 0.0f;
  if (l < NK) {
    for (int ij = s; ij < NIJ; ij += 8)
      acc = fmaf(Y[ij * NK + k], Y[ij * NK + l], acc);
  }
  acc = oct_sum(acc);
  if (s == 0 && l < NK) Mout[k * NK + l] = acc;
}

// ---------------- kernel D1: single-wave Householder tridiag (R16, PINNED) ----
// One wave, A[80x80] in VGPRs as f32x2 col-pairs: lane l=(br<<3)|bc owns rows
// [10br,+10) x col-pairs [5bc,+5). Zero barriers, zero LDS.
// R15/R17/R18 restructures all regressed — do not modify the schedule.
__global__ __launch_bounds__(64, 1) void tridiag_kernel(const float* __restrict__ Min,
                                                        float* __restrict__ ws2) {
  const int l = threadIdx.x;
  const int br = l >> 3, bc = l & 7;
  f32x2 A2[10][5];
#pragma unroll
  for (int r = 0; r < 10; ++r) {
    const int g = 10 * br + r;
#pragma unroll
    for (int c2 = 0; c2 < 5; ++c2) {
      const int gc0 = 10 * bc + 2 * c2;
      A2[r][c2][0] = (g < 77 && gc0 < 77) ? Min[g * 77 + gc0] : 0.0f;
      A2[r][c2][1] = (g < 77 && gc0 + 1 < 77) ? Min[g * 77 + gc0 + 1] : 0.0f;
    }
  }

  // prologue: broadcast row 0 (col-chunks from lane bc, row-chunks from lane br)
  float rc[10], rr[10];
#pragma unroll
  for (int c2 = 0; c2 < 5; ++c2) {
    rc[2 * c2]     = __shfl(A2[0][c2][0], bc, 64);
    rc[2 * c2 + 1] = __shfl(A2[0][c2][1], bc, 64);
    rr[2 * c2]     = __shfl(A2[0][c2][0], br, 64);
    rr[2 * c2 + 1] = __shfl(A2[0][c2][1], br, 64);
  }

#pragma unroll 1
  for (int kb = 0; kb < 8; ++kb) {
#pragma unroll
    for (int ko = 0; ko < 10; ++ko) {
      if (kb == 7 && ko >= 5) break;           // k stops at 74
      const int k = kb * 10 + ko;
      const int nko = (ko + 1) % 10;           // literal after unroll
      const int nkb = kb + (ko == 9 ? 1 : 0);
      const int nic = nkb * 8 + bc, nir = nkb * 8 + br;

      // sigma2 partials (br==0 lanes = oct 0) -> 3-hop oct_sum + readfirstlane
      float part = 0.0f;
      if (br == 0) {
#pragma unroll
        for (int c2 = 0; c2 < 5; ++c2) {
          const int gc0 = 10 * bc + 2 * c2;
          const float x0 = rc[2 * c2], xv = rc[2 * c2 + 1];
          part += (gc0 > k) ? x0 * x0 : 0.0f;
          part += (gc0 + 1 > k) ? xv * xv : 0.0f;
        }
      }
      part = oct_sum(part);
      const float sigma2 = readlane0(part);
      if (sigma2 < 1e-26f) {                   // uniform branch, rare
        if (l == 0) ws2[80 + k] = 0.0f;
#pragma unroll
        for (int c2 = 0; c2 < 5; ++c2) {       // still pipeline next bcast
          rc[2 * c2]     = __shfl(A2[nko][c2][0], nic, 64);
          rc[2 * c2 + 1] = __shfl(A2[nko][c2][1], nic, 64);
          rr[2 * c2]     = __shfl(A2[nko][c2][0], nir, 64);
          rr[2 * c2 + 1] = __shfl(A2[nko][c2][1], nir, 64);
        }
        continue;
      }
      // x1 = A[k][k+1]: col k+1 sits in rc[nko] of lanes with bc==nkb
      const float x1 = readlaneN(rc[nko], nkb);
      const float sigma = __builtin_amdgcn_sqrtf(sigma2);
      const float alpha = (x1 >= 0.0f) ? -sigma : sigma;
      const float beta = __builtin_amdgcn_rcpf(fmaf(-alpha, x1, sigma2));
      const float xha = x1 - alpha;
      if (l == 0) ws2[80 + k] = alpha;

      // v over own cols (from rc) and own rows (from rr) — both local
      f32x2 vc2[5];
      float vr[10];
#pragma unroll
      for (int c2 = 0; c2 < 5; ++c2) {
        const int gc0 = 10 * bc + 2 * c2;
        vc2[c2][0] = (gc0 > k) ? ((gc0 == k + 1) ? xha : rc[2 * c2]) : 0.0f;
        vc2[c2][1] = (gc0 + 1 > k) ? ((gc0 + 1 == k + 1) ? xha : rc[2 * c2 + 1]) : 0.0f;
        const int gr0 = 10 * br + 2 * c2;
        vr[2 * c2] = (gr0 > k) ? ((gr0 == k + 1) ? xha : rr[2 * c2]) : 0.0f;
        vr[2 * c2 + 1] = (gr0 + 1 > k) ? ((gr0 + 1 == k + 1) ? xha : rr[2 * c2 + 1]) : 0.0f;
      }

      // p = beta * A v (packed fma; rows independent)
      float p[10];
#pragma unroll
      for (int r = 0; r < 10; ++r) {
        f32x2 a = (f32x2){0.f, 0.f};
#pragma unroll
        for (int c2 = 0; c2 < 5; ++c2) a = pk_fma(A2[r][c2], vc2[c2], a);
        p[r] = a[0] + a[1];
      }
#pragma unroll
      for (int r = 0; r < 10; ++r) {
        p[r] = oct_sum(p[r]) * beta;
        p[r] = (10 * br + r > k) ? p[r] : 0.0f;
      }

      // prefetch p-by-columns NOW (hides under the K reduction)
      f32x2 pc2[5];
#pragma unroll
      for (int c2 = 0; c2 < 5; ++c2) {
        pc2[c2][0] = __shfl(p[2 * c2], 9 * bc, 64);
        pc2[c2][1] = __shfl(p[2 * c2 + 1], 9 * bc, 64);
      }

      // K = p . v (rows counted once: bc==0 lanes)
      float kp = 0.0f;
      if (bc == 0) {
#pragma unroll
        for (int r = 0; r < 10; ++r) kp = fmaf(p[r], vr[r], kp);
      }
      kp = wave_sum(kp);
      const float hb = 0.5f * beta * readlane63(kp);

      // w by rows (local); wc by cols LOCAL from prefetched pc
      float w[10];
#pragma unroll
      for (int r = 0; r < 10; ++r) w[r] = fmaf(-hb, vr[r], p[r]);
      const f32x2 mhb = (f32x2){-hb, -hb};
      f32x2 wc2[5];
#pragma unroll
      for (int c2 = 0; c2 < 5; ++c2) wc2[c2] = pk_fma(mhb, vc2[c2], pc2[c2]);

      // rank-2 update: pivot row nko FIRST, issue next broadcast, then rest
      {
        const f32x2 nv = (f32x2){-vr[nko], -vr[nko]};
        const f32x2 nw = (f32x2){-w[nko], -w[nko]};
#pragma unroll
        for (int c2 = 0; c2 < 5; ++c2)
          A2[nko][c2] = pk_fma(nv, wc2[c2], pk_fma(nw, vc2[c2], A2[nko][c2]));
      }
#pragma unroll
      for (int c2 = 0; c2 < 5; ++c2) {
        rc[2 * c2]     = __shfl(A2[nko][c2][0], nic, 64);
        rc[2 * c2 + 1] = __shfl(A2[nko][c2][1], nic, 64);
        rr[2 * c2]     = __shfl(A2[nko][c2][0], nir, 64);
        rr[2 * c2 + 1] = __shfl(A2[nko][c2][1], nir, 64);
      }
#pragma unroll
      for (int r = 0; r < 10; ++r) {
        if (r == nko) continue;
        const f32x2 nv = (f32x2){-vr[r], -vr[r]};
        const f32x2 nw = (f32x2){-w[r], -w[r]};
#pragma unroll
        for (int c2 = 0; c2 < 5; ++c2)
          A2[r][c2] = pk_fma(nv, wc2[c2], pk_fma(nw, vc2[c2], A2[r][c2]));
      }
    }
  }

  // gather tridiagonal: diag from lanes br==bc, last offdiag from lane 63
  if (br == bc) {
#pragma unroll
    for (int e = 0; e < 10; ++e)
      ws2[10 * br + e] = (e & 1) ? A2[e][e / 2][1] : A2[e][e / 2][0];
  }
  if (l == 63) ws2[80 + 75] = A2[6][2][1];     // A[76][75]
}

// ---------------- kernel D2: bisection (verified 9-section, 640 thr) ----------
__global__ __launch_bounds__(EIGT) void bisect_kernel(const float* __restrict__ ws2,
                                                      float* __restrict__ eout) {
  __shared__ float dsh[80], esh[80], e2sh[80];
  __shared__ float red[10], red2[10];
  const int t = threadIdx.x;
  const int lane = t & 63, wv = t >> 6;
  if (t < 80) {
    dsh[t] = ws2[t];
    esh[t] = (t < 76) ? ws2[80 + t] : 0.0f;
  }
  __syncthreads();
  if (t < 76) e2sh[t] = esh[t] * esh[t];

  // Gershgorin bounds (parallel reduce)
  float lo_ = 1e30f, hi_ = -1e30f;
  if (t < 77) {
    const float r = ((t > 0) ? fabsf(esh[t - 1]) : 0.0f) +
                    ((t < 76) ? fabsf(esh[t]) : 0.0f);
    lo_ = dsh[t] - r;
    hi_ = dsh[t] + r;
  }
#pragma unroll
  for (int off = 1; off < 64; off <<= 1) {
    lo_ = fminf(lo_, __shfl_xor(lo_, off, 64));
    hi_ = fmaxf(hi_, __shfl_xor(hi_, off, 64));
  }
  if (lane == 0) { red[wv] = lo_; red2[wv] = hi_; }
  __syncthreads();                          // also fences e2sh/dsh
  lo_ = red[0]; hi_ = red2[0];
#pragma unroll
  for (int u = 1; u < 10; ++u) { lo_ = fminf(lo_, red[u]); hi_ = fmaxf(hi_, red2[u]); }
  const float span = hi_ - lo_;
  const float glo = lo_ - 0.001f * span - 1e-6f;
  const float ghi = hi_ + 0.001f * span + 1e-6f;

  // 9-section search via Sturm count: 8 probe lanes per eigenvalue, 13 rounds
  {
    const int e = t >> 3;        // eigenvalue index 0..79 (77..79 inactive)
    const int s = t & 7;         // probe lane within oct
    const int g = (t & 63) >> 3; // oct group within wave
    float lo = glo, hi = ghi;
    for (int r = 0; r < 13; ++r) {
      const float step = (hi - lo) * (1.0f / 9.0f);
      const float x = fmaf(step, (float)(s + 1), lo);
      float q = dsh[0] - x;
      int cnt = (q < 0.0f);
#pragma unroll 4
      for (int i = 1; i < 77; ++i) {
        q = (fabsf(q) < 1e-30f) ? -1e-30f : q;
        q = dsh[i] - x - e2sh[i - 1] * __builtin_amdgcn_rcpf(q);
        cnt += (q < 0.0f);
      }
      const unsigned long long mask = __ballot(cnt > e);
      const int b = (int)((mask >> (g * 8)) & 0xFFull);
      const int z = b ? __builtin_ctz(b) : 8;   // probes with cnt<=e
      const float nlo = fmaf(step, (float)z, lo);
      hi = (z == 8) ? hi : fmaf(step, (float)(z + 1), lo);
      lo = nlo;
    }
    if (s == 0 && e < 77) eout[76 - e] = 0.5f * (lo + hi);  // descending
  }
}

// ---------------- launch ----------------
extern "C" void kernel_launch(void* const* d_in, const int* in_sizes, int n_in,
                              void* d_out, int out_size, void* d_ws, size_t ws_size,
                              hipStream_t stream) {
  const float* omega  = (const float*)d_in[0];
  const float* Phi    = (const float*)d_in[1];
  const float* metric = (const float*)d_in[2];
  for (int q = 0; q < n_in && q < 3; ++q) {
    if (in_sizes[q] == SZ_OMEGA)       omega  = (const float*)d_in[q];
    else if (in_sizes[q] == SZ_PHI)    Phi    = (const float*)d_in[q];
    else if (in_sizes[q] == SZ_METRIC) metric = (const float*)d_in[q];
  }

  float* out = (float*)d_out;
  float* ws  = (float*)d_ws;

  const int priv = (ws_size >= WS_NEED_PRV) ? 1 : 0;
  const int nslot = priv ? GRID_B : NSLOT;
  float* ws2 = ws + (priv ? WS2OFF_PRV : WS2OFF_FB);

  // out[0 .. Y_SIZE)           : finalized Y
  // out[VOLOFF .. VOLOFF+4096) : vol[n] (temp, overwritten by gram's M)
  // out[VSUM]                  : volsum (temp, overwritten by gram's M)
  // ws slots                   : per-block (priv) or 16 shared (fallback)
  hipMemsetAsync(d_out, 0, (size_t)out_size * sizeof(float), stream);
  if (!priv)   // privatized slots are fully overwritten -> no memset needed
    hipMemsetAsync(d_ws, 0, (size_t)WS2OFF_FB * sizeof(float), stream);

  hipLaunchKernelGGL(vol_kernel, dim3(NBATCH / 256), dim3(256), 0, stream, metric, out);
  hipLaunchKernelGGL(contract_kernel, dim3(GRID_B), dim3(BLK), 0, stream,
                     omega, Phi, out, ws, priv);
  hipLaunchKernelGGL(finalize_y, dim3((NPAIR * NK + 255) / 256), dim3(256), 0, stream,
                     ws, out, nslot);
  hipLaunchKernelGGL(gram_kernel, dim3(NK), dim3(EIGT), 0, stream,
                     out, out + Y_SIZE);
  hipLaunchKernelGGL(tridiag_kernel, dim3(1), dim3(64), 0, stream,
                     out + Y_SIZE, ws2);
  hipLaunchKernelGGL(bisect_kernel, dim3(1), dim3(EIGT), 0, stream,
                     ws2, out + Y_SIZE + M_SIZE);
}